// Round 3
// baseline (697.634 us; speedup 1.0000x reference)
//
#include <hip/hip_runtime.h>
#include <hip/hip_bf16.h>
#include <cmath>

// Problem constants
constexpr int Tq  = 2048;   // sequence length
constexpr int Dm  = 1024;   // model dim
constexpr int NHC = 16;     // heads
constexpr int HDC = 64;     // head dim
constexpr int TDC = 256;    // T / STRIDE
constexpr int KSEL = 26;    // ceil(204 / 8): 26th-largest distinct value

// ---------------------------------------------------------------------------
// Generic fp32 GEMM: C[M][1024] = A[M][1024] * B[1024][1024]^T  (dot of rows)
// ---------------------------------------------------------------------------
__global__ __launch_bounds__(256) void gemm_xwT(
    const float* __restrict__ A, const float* __restrict__ B,
    float* __restrict__ C) {
  const int K = 1024, N = 1024;
  __shared__ float As[32][68];
  __shared__ float Bs[32][68];
  int tid = threadIdx.x;
  int tx = tid & 15, ty = tid >> 4;
  int n0 = blockIdx.x * 64, m0 = blockIdx.y * 64;
  float acc[4][4] = {};
  for (int k0 = 0; k0 < K; k0 += 32) {
#pragma unroll
    for (int q = 0; q < 2; ++q) {
      int f = tid * 2 + q;
      int row = f >> 3, c4 = f & 7;
      float4 av = *(const float4*)&A[(size_t)(m0 + row) * K + k0 + c4 * 4];
      float4 bv = *(const float4*)&B[(size_t)(n0 + row) * K + k0 + c4 * 4];
      As[c4 * 4 + 0][row] = av.x; As[c4 * 4 + 1][row] = av.y;
      As[c4 * 4 + 2][row] = av.z; As[c4 * 4 + 3][row] = av.w;
      Bs[c4 * 4 + 0][row] = bv.x; Bs[c4 * 4 + 1][row] = bv.y;
      Bs[c4 * 4 + 2][row] = bv.z; Bs[c4 * 4 + 3][row] = bv.w;
    }
    __syncthreads();
#pragma unroll
    for (int k = 0; k < 32; ++k) {
      float a[4], b[4];
#pragma unroll
      for (int i = 0; i < 4; ++i) { a[i] = As[k][ty * 4 + i]; b[i] = Bs[k][tx * 4 + i]; }
#pragma unroll
      for (int i = 0; i < 4; ++i)
#pragma unroll
        for (int j = 0; j < 4; ++j) acc[i][j] += a[i] * b[j];
    }
    __syncthreads();
  }
#pragma unroll
  for (int i = 0; i < 4; ++i)
#pragma unroll
    for (int j = 0; j < 4; ++j)
      C[(size_t)(m0 + ty * 4 + i) * N + n0 + tx * 4 + j] = acc[i][j];
}

// ---------------------------------------------------------------------------
// Downsampled scores: Sd[h][iq][jk] = 0.125 * dot(Q[iq*8, h], K[jk*8, h])
// ---------------------------------------------------------------------------
__global__ __launch_bounds__(256) void sd_kernel(
    const float* __restrict__ Q, const float* __restrict__ K,
    float* __restrict__ Sd) {
  __shared__ float Qs[64][68];
  __shared__ float Ks[64][68];
  int jk0 = blockIdx.x * 64, iq0 = blockIdx.y * 64, h = blockIdx.z;
  int tid = threadIdx.x, tx = tid & 15, ty = tid >> 4;
#pragma unroll
  for (int q = 0; q < 4; ++q) {
    int f = tid * 4 + q;
    int row = f >> 4, c4 = f & 15;
    float4 q4 = *(const float4*)&Q[((size_t)(iq0 + row) * 8) * Dm + h * HDC + c4 * 4];
    float4 k4 = *(const float4*)&K[((size_t)(jk0 + row) * 8) * Dm + h * HDC + c4 * 4];
    Qs[c4 * 4 + 0][row] = q4.x; Qs[c4 * 4 + 1][row] = q4.y;
    Qs[c4 * 4 + 2][row] = q4.z; Qs[c4 * 4 + 3][row] = q4.w;
    Ks[c4 * 4 + 0][row] = k4.x; Ks[c4 * 4 + 1][row] = k4.y;
    Ks[c4 * 4 + 2][row] = k4.z; Ks[c4 * 4 + 3][row] = k4.w;
  }
  __syncthreads();
  float acc[4][4] = {};
#pragma unroll
  for (int k = 0; k < 64; ++k) {
    float a[4], b[4];
#pragma unroll
    for (int i = 0; i < 4; ++i) { a[i] = Qs[k][ty * 4 + i]; b[i] = Ks[k][tx * 4 + i]; }
#pragma unroll
    for (int i = 0; i < 4; ++i)
#pragma unroll
      for (int j = 0; j < 4; ++j) acc[i][j] += a[i] * b[j];
  }
#pragma unroll
  for (int i = 0; i < 4; ++i)
#pragma unroll
    for (int j = 0; j < 4; ++j)
      Sd[(size_t)(h * TDC + iq0 + ty * 4 + i) * TDC + jk0 + tx * 4 + j] =
          acc[i][j] * 0.125f;
}

// ---------------------------------------------------------------------------
// 26th-largest of each 256-value Sd row.
// ---------------------------------------------------------------------------
__global__ __launch_bounds__(64) void kth_kernel(
    const float* __restrict__ Sd, float* __restrict__ kth) {
  int b = blockIdx.x;
  int lane = threadIdx.x;
  const float* row = &Sd[(size_t)b * TDC];
  float v[4];
#pragma unroll
  for (int j = 0; j < 4; ++j) v[j] = row[lane + 64 * j];
  float ans = 0.f;
  for (int it = 0; it < KSEL; ++it) {
    float lm = fmaxf(fmaxf(v[0], v[1]), fmaxf(v[2], v[3]));
#pragma unroll
    for (int off = 1; off < 64; off <<= 1) lm = fmaxf(lm, __shfl_xor(lm, off));
    if (it == KSEL - 1) { ans = lm; break; }
    unsigned long long ball =
        __ballot(v[0] == lm || v[1] == lm || v[2] == lm || v[3] == lm);
    int first = __ffsll(ball) - 1;
    if (lane == first) {
      if (v[0] == lm) v[0] = -INFINITY;
      else if (v[1] == lm) v[1] = -INFINITY;
      else if (v[2] == lm) v[2] = -INFINITY;
      else v[3] = -INFINITY;
    }
  }
  if (lane == 0) kth[b] = ans;
}

// ---------------------------------------------------------------------------
// Per-head mean of V over all 2048 rows (for the all-masked uniform regime).
// grid = 16 heads, block = 64 (one thread per d).
// ---------------------------------------------------------------------------
__global__ __launch_bounds__(64) void vmean_kernel(
    const float* __restrict__ V, float* __restrict__ Vm) {
  int h = blockIdx.x, d = threadIdx.x;
  float s = 0.f;
  for (int t = 0; t < Tq; ++t) s += V[(size_t)t * Dm + h * HDC + d];
  Vm[h * HDC + d] = s * (1.f / 2048.f);
}

// ---------------------------------------------------------------------------
// Fused causal flash attention with DSA mask, replicating the reference's
// fp32 op order exactly:
//   sf = fl(Sd*u); kth_v = fl(Sd26*u); arg = fl((sf-kth_v)*10)
//   mask = expit_fp32(arg)  (branchy form, like jax.nn.sigmoid)
//   pen = fl((1-mask)*(-1e9));  logit = fl(s*0.125 + pen)   [s*0.125 exact]
// All-masked rows (max logit == -1e9 exactly): reference softmax is UNIFORM
// over the whole 2048-row (future included!) -> output = Vmean[h].
// ---------------------------------------------------------------------------
__global__ __launch_bounds__(256) void attn_kernel(
    const float* __restrict__ Q, const float* __restrict__ K,
    const float* __restrict__ V, const float* __restrict__ U,
    const float* __restrict__ Sd, const float* __restrict__ kth,
    const float* __restrict__ Vmean,
    float* __restrict__ AO) {
  __shared__ float Qs[64][68];
  __shared__ float Ks[64][68];
  __shared__ float Vs[64][68];
  __shared__ float Ps[64][68];
  int qt = blockIdx.x, h = blockIdx.y;
  int tid = threadIdx.x, tx = tid & 15, ty = tid >> 4;
  int i0 = qt * 64;
#pragma unroll
  for (int q = 0; q < 4; ++q) {
    int f = tid * 4 + q;
    int row = f >> 4, c4 = f & 15;
    float4 v4 = *(const float4*)&Q[(size_t)(i0 + row) * Dm + h * HDC + c4 * 4];
    Qs[c4 * 4 + 0][row] = v4.x; Qs[c4 * 4 + 1][row] = v4.y;
    Qs[c4 * 4 + 2][row] = v4.z; Qs[c4 * 4 + 3][row] = v4.w;
  }
  float mrun[4], lrun[4], acc[4][4] = {};
#pragma unroll
  for (int i = 0; i < 4; ++i) { mrun[i] = -INFINITY; lrun[i] = 0.f; }
  int gi = i0 + ty * 4;
  float uf[4];
#pragma unroll
  for (int i = 0; i < 4; ++i) {
    float uu = U[gi + i];
    uf[i] = 1.f + fminf(fmaxf(uu, 0.f), 1.f);
  }
  float kv = kth[h * TDC + (gi >> 3)];
  const float* SdRow = Sd + (size_t)(h * TDC + (gi >> 3)) * TDC;

  for (int jt = 0; jt <= qt; ++jt) {
    int j0 = jt * 64;
#pragma unroll
    for (int q = 0; q < 4; ++q) {
      int f = tid * 4 + q;
      int row = f >> 4, c4 = f & 15;
      float4 k4 = *(const float4*)&K[(size_t)(j0 + row) * Dm + h * HDC + c4 * 4];
      float4 vv4 = *(const float4*)&V[(size_t)(j0 + row) * Dm + h * HDC + c4 * 4];
      Ks[c4 * 4 + 0][row] = k4.x; Ks[c4 * 4 + 1][row] = k4.y;
      Ks[c4 * 4 + 2][row] = k4.z; Ks[c4 * 4 + 3][row] = k4.w;
      *(float4*)&Vs[row][c4 * 4] = vv4;
    }
    __syncthreads();
    float s[4][4] = {};
#pragma unroll
    for (int k = 0; k < 64; ++k) {
      float a[4], b[4];
#pragma unroll
      for (int i = 0; i < 4; ++i) { a[i] = Qs[k][ty * 4 + i]; b[i] = Ks[k][tx * 4 + i]; }
#pragma unroll
      for (int i = 0; i < 4; ++i)
#pragma unroll
        for (int j = 0; j < 4; ++j) s[i][j] += a[i] * b[j];
    }
    // mask + logits + online softmax (4 cols of this thread share one j-block)
    float sdv = SdRow[(j0 + tx * 4) >> 3];
#pragma unroll
    for (int i = 0; i < 4; ++i) {
      // replicate reference fp32 op order exactly
      float sfv  = sdv * uf[i];
      float kthv = kv * uf[i];
      float arg  = (sfv - kthv) * 10.f;
      float mask;
      if (arg >= 0.f) {
        mask = 1.f / (1.f + expf(-arg));
      } else {
        float e = expf(arg);
        mask = e / (1.f + e);
      }
      float pen = (1.f - mask) * (-1.0e9f);
      float lg[4];
#pragma unroll
      for (int j = 0; j < 4; ++j) {
        int gj = j0 + tx * 4 + j;
        lg[j] = s[i][j] * 0.125f + ((gj <= gi + i) ? pen : -1.0e9f);
      }
      float tmax = fmaxf(fmaxf(lg[0], lg[1]), fmaxf(lg[2], lg[3]));
#pragma unroll
      for (int off = 1; off < 16; off <<= 1) tmax = fmaxf(tmax, __shfl_xor(tmax, off));
      float mnew = fmaxf(mrun[i], tmax);
      float scale = expf(mrun[i] - mnew);
      float p[4], psum = 0.f;
#pragma unroll
      for (int j = 0; j < 4; ++j) { p[j] = expf(lg[j] - mnew); psum += p[j]; }
#pragma unroll
      for (int off = 1; off < 16; off <<= 1) psum += __shfl_xor(psum, off);
      lrun[i] = lrun[i] * scale + psum;
      mrun[i] = mnew;
#pragma unroll
      for (int d = 0; d < 4; ++d) acc[i][d] *= scale;
#pragma unroll
      for (int j = 0; j < 4; ++j) Ps[tx * 4 + j][ty * 4 + i] = p[j];
    }
    __syncthreads();
#pragma unroll 8
    for (int j = 0; j < 64; ++j) {
      float pv[4], vv[4];
#pragma unroll
      for (int i = 0; i < 4; ++i) { pv[i] = Ps[j][ty * 4 + i]; vv[i] = Vs[j][tx * 4 + i]; }
#pragma unroll
      for (int i = 0; i < 4; ++i)
#pragma unroll
        for (int d = 0; d < 4; ++d) acc[i][d] += pv[i] * vv[d];
    }
    __syncthreads();
  }
#pragma unroll
  for (int i = 0; i < 4; ++i) {
    if (mrun[i] == -1.0e9f) {
      // all-masked row: reference softmax is uniform over ALL 2048 entries
#pragma unroll
      for (int d = 0; d < 4; ++d)
        AO[(size_t)(gi + i) * Dm + h * HDC + tx * 4 + d] =
            Vmean[h * HDC + tx * 4 + d];
    } else {
      float inv = 1.f / lrun[i];
#pragma unroll
      for (int d = 0; d < 4; ++d)
        AO[(size_t)(gi + i) * Dm + h * HDC + tx * 4 + d] = acc[i][d] * inv;
    }
  }
}

// ---------------------------------------------------------------------------
extern "C" void kernel_launch(void* const* d_in, const int* in_sizes, int n_in,
                              void* d_out, int out_size, void* d_ws, size_t ws_size,
                              hipStream_t stream) {
  const float* x  = (const float*)d_in[0];
  const float* U  = (const float*)d_in[1];
  const float* wq = (const float*)d_in[2];
  const float* wk = (const float*)d_in[3];
  const float* wv = (const float*)d_in[4];
  const float* wo = (const float*)d_in[5];
  float* out = (float*)d_out;

  float* ws = (float*)d_ws;
  const size_t TD_ = (size_t)Tq * Dm;
  float* Q    = ws;
  float* Kp   = Q  + TD_;
  float* Vp   = Kp + TD_;
  float* AO   = Vp + TD_;
  float* Sd   = AO + TD_;
  float* kth  = Sd + (size_t)NHC * TDC * TDC;
  float* Vm   = kth + (size_t)NHC * TDC;

  dim3 bb(256);
  dim3 gg(Dm / 64, Tq / 64);
  gemm_xwT<<<gg, bb, 0, stream>>>(x, wq, Q);
  gemm_xwT<<<gg, bb, 0, stream>>>(x, wk, Kp);
  gemm_xwT<<<gg, bb, 0, stream>>>(x, wv, Vp);
  sd_kernel<<<dim3(4, 4, NHC), bb, 0, stream>>>(Q, Kp, Sd);
  kth_kernel<<<dim3(NHC * TDC), dim3(64), 0, stream>>>(Sd, kth);
  vmean_kernel<<<dim3(NHC), dim3(64), 0, stream>>>(Vp, Vm);
  attn_kernel<<<dim3(Tq / 64, NHC), bb, 0, stream>>>(Q, Kp, Vp, U, Sd, kth, Vm, AO);
  gemm_xwT<<<gg, bb, 0, stream>>>(AO, wo, out);
}

// Round 5
// 379.541 us; speedup vs baseline: 1.8381x; 1.8381x over previous
//
#include <hip/hip_runtime.h>
#include <hip/hip_bf16.h>
#include <cmath>

typedef __attribute__((ext_vector_type(8))) short bf16x8;
typedef __attribute__((ext_vector_type(4))) short bf16x4;
typedef __attribute__((ext_vector_type(4))) float f32x4;

constexpr int Tq  = 2048;
constexpr int Dm  = 1024;
constexpr int NHC = 16;
constexpr int HDC = 64;
constexpr int TDC = 256;
constexpr int KSEL = 26;   // ceil(204/8): 26th-largest distinct value
constexpr int CH  = 8;     // j-tiles (of 64) per split-j chunk

__device__ inline ushort f2bf(float x) {
  union { float f; unsigned u; } v; v.f = x;
  return (ushort)((v.u + 0x7FFF + ((v.u >> 16) & 1)) >> 16);
}
__device__ inline float bf2f(ushort b) {
  union { unsigned u; float f; } v; v.u = ((unsigned)b) << 16;
  return v.f;
}

// ---------------------------------------------------------------------------
// fp32 GEMM (exactness required for mask path): C = A * B^T
// ---------------------------------------------------------------------------
__global__ __launch_bounds__(256) void gemm_xwT(
    const float* __restrict__ A, const float* __restrict__ B,
    float* __restrict__ C) {
  const int K = 1024, N = 1024;
  __shared__ float As[32][68];
  __shared__ float Bs[32][68];
  int tid = threadIdx.x;
  int tx = tid & 15, ty = tid >> 4;
  int n0 = blockIdx.x * 64, m0 = blockIdx.y * 64;
  float acc[4][4] = {};
  for (int k0 = 0; k0 < K; k0 += 32) {
#pragma unroll
    for (int q = 0; q < 2; ++q) {
      int f = tid * 2 + q;
      int row = f >> 3, c4 = f & 7;
      float4 av = *(const float4*)&A[(size_t)(m0 + row) * K + k0 + c4 * 4];
      float4 bv = *(const float4*)&B[(size_t)(n0 + row) * K + k0 + c4 * 4];
      As[c4 * 4 + 0][row] = av.x; As[c4 * 4 + 1][row] = av.y;
      As[c4 * 4 + 2][row] = av.z; As[c4 * 4 + 3][row] = av.w;
      Bs[c4 * 4 + 0][row] = bv.x; Bs[c4 * 4 + 1][row] = bv.y;
      Bs[c4 * 4 + 2][row] = bv.z; Bs[c4 * 4 + 3][row] = bv.w;
    }
    __syncthreads();
#pragma unroll
    for (int k = 0; k < 32; ++k) {
      float a[4], b[4];
#pragma unroll
      for (int i = 0; i < 4; ++i) { a[i] = As[k][ty * 4 + i]; b[i] = Bs[k][tx * 4 + i]; }
#pragma unroll
      for (int i = 0; i < 4; ++i)
#pragma unroll
        for (int j = 0; j < 4; ++j) acc[i][j] += a[i] * b[j];
    }
    __syncthreads();
  }
#pragma unroll
  for (int i = 0; i < 4; ++i)
#pragma unroll
    for (int j = 0; j < 4; ++j)
      C[(size_t)(m0 + ty * 4 + i) * N + n0 + tx * 4 + j] = acc[i][j];
}

// ---------------------------------------------------------------------------
// fp32 -> (bf16 hi, bf16 lo) split cast, 4 elems/thread
// ---------------------------------------------------------------------------
__global__ __launch_bounds__(256) void cast_split(
    const float* __restrict__ in, ushort* __restrict__ hi,
    ushort* __restrict__ lo) {
  int base = (blockIdx.x * 256 + threadIdx.x) * 4;
  float4 v = *(const float4*)&in[base];
  ushort h0 = f2bf(v.x), h1 = f2bf(v.y), h2 = f2bf(v.z), h3 = f2bf(v.w);
  *(ushort4*)&hi[base] = make_ushort4(h0, h1, h2, h3);
  *(ushort4*)&lo[base] = make_ushort4(
      f2bf(v.x - bf2f(h0)), f2bf(v.y - bf2f(h1)),
      f2bf(v.z - bf2f(h2)), f2bf(v.w - bf2f(h3)));
}

// fp32 [t][1024] Q,K -> split bf16 [h][t][64] hi/lo
__global__ __launch_bounds__(256) void remap_qk_split(
    const float* __restrict__ Q, const float* __restrict__ K,
    ushort* __restrict__ Qh, ushort* __restrict__ Ql,
    ushort* __restrict__ Kh, ushort* __restrict__ Kl) {
  int gid = blockIdx.x * 256 + threadIdx.x;
  int t = gid >> 8;
  int c4 = (gid & 255) * 4;
  float4 q = *(const float4*)&Q[(size_t)t * Dm + c4];
  float4 k = *(const float4*)&K[(size_t)t * Dm + c4];
  int h = c4 >> 6, d = c4 & 63;
  size_t o = (size_t)h * Tq * HDC + (size_t)t * HDC + d;
  ushort qh0 = f2bf(q.x), qh1 = f2bf(q.y), qh2 = f2bf(q.z), qh3 = f2bf(q.w);
  ushort kh0 = f2bf(k.x), kh1 = f2bf(k.y), kh2 = f2bf(k.z), kh3 = f2bf(k.w);
  *(ushort4*)&Qh[o] = make_ushort4(qh0, qh1, qh2, qh3);
  *(ushort4*)&Kh[o] = make_ushort4(kh0, kh1, kh2, kh3);
  *(ushort4*)&Ql[o] = make_ushort4(
      f2bf(q.x - bf2f(qh0)), f2bf(q.y - bf2f(qh1)),
      f2bf(q.z - bf2f(qh2)), f2bf(q.w - bf2f(qh3)));
  *(ushort4*)&Kl[o] = make_ushort4(
      f2bf(k.x - bf2f(kh0)), f2bf(k.y - bf2f(kh1)),
      f2bf(k.z - bf2f(kh2)), f2bf(k.w - bf2f(kh3)));
}

// ---------------------------------------------------------------------------
// Split-bf16 MFMA GEMM (fp32-quality): C = (Ah+Al)*(Bh+Bl)^T, drop Al*Bl.
// MODE 0: fp32 row-major out.  MODE 1: split bf16 transposed out Vt[h][d][t].
// ---------------------------------------------------------------------------
template <int MODE>
__global__ __launch_bounds__(256) void gemm_split(
    const ushort* __restrict__ Ah, const ushort* __restrict__ Al,
    const ushort* __restrict__ Bh, const ushort* __restrict__ Bl,
    float* __restrict__ Cf, ushort* __restrict__ Chi, ushort* __restrict__ Clo) {
  __shared__ ushort AhS[64][64], AlS[64][64], BhS[64][64], BlS[64][64];
  int tid = threadIdx.x, w = tid >> 6, l = tid & 63, l15 = l & 15, lg = l >> 4;
  int wm = (w >> 1) * 32, wn = (w & 1) * 32;
  int m0 = blockIdx.y * 64, n0 = blockIdx.x * 64;
  f32x4 acc[2][2] = {};
  for (int k0 = 0; k0 < Dm; k0 += 64) {
    __syncthreads();
#pragma unroll
    for (int q = 0; q < 2; ++q) {
      int f = tid * 2 + q, row = f >> 3, c8 = f & 7;
      size_t ao = (size_t)(m0 + row) * Dm + k0 + c8 * 8;
      size_t bo = (size_t)(n0 + row) * Dm + k0 + c8 * 8;
      int sc = (c8 ^ (row & 7)) * 8;
      *(bf16x8*)&AhS[row][sc] = *(const bf16x8*)&Ah[ao];
      *(bf16x8*)&AlS[row][sc] = *(const bf16x8*)&Al[ao];
      *(bf16x8*)&BhS[row][sc] = *(const bf16x8*)&Bh[bo];
      *(bf16x8*)&BlS[row][sc] = *(const bf16x8*)&Bl[bo];
    }
    __syncthreads();
#pragma unroll
    for (int kst = 0; kst < 2; ++kst) {
      bf16x8 ah[2], al[2], bh[2], bl[2];
#pragma unroll
      for (int i = 0; i < 2; ++i) {
        int ar = wm + i * 16 + l15;
        int sa = ((kst * 4 + lg) ^ (ar & 7)) * 8;
        ah[i] = *(const bf16x8*)&AhS[ar][sa];
        al[i] = *(const bf16x8*)&AlS[ar][sa];
        int br = wn + i * 16 + l15;
        int sb = ((kst * 4 + lg) ^ (br & 7)) * 8;
        bh[i] = *(const bf16x8*)&BhS[br][sb];
        bl[i] = *(const bf16x8*)&BlS[br][sb];
      }
#pragma unroll
      for (int i = 0; i < 2; ++i)
#pragma unroll
        for (int j = 0; j < 2; ++j) {
          acc[i][j] = __builtin_amdgcn_mfma_f32_16x16x32_bf16(ah[i], bh[j], acc[i][j], 0, 0, 0);
          acc[i][j] = __builtin_amdgcn_mfma_f32_16x16x32_bf16(al[i], bh[j], acc[i][j], 0, 0, 0);
          acc[i][j] = __builtin_amdgcn_mfma_f32_16x16x32_bf16(ah[i], bl[j], acc[i][j], 0, 0, 0);
        }
    }
  }
#pragma unroll
  for (int i = 0; i < 2; ++i)
#pragma unroll
    for (int j = 0; j < 2; ++j) {
      int r0 = m0 + wm + i * 16 + lg * 4;
      int cc = n0 + wn + j * 16 + l15;
      if (MODE == 0) {
#pragma unroll
        for (int rg = 0; rg < 4; ++rg)
          Cf[(size_t)(r0 + rg) * Dm + cc] = acc[i][j][rg];
      } else {
        bf16x4 ph, pl;
#pragma unroll
        for (int rg = 0; rg < 4; ++rg) {
          float v = acc[i][j][rg];
          ushort hh = f2bf(v);
          ph[rg] = (short)hh;
          pl[rg] = (short)f2bf(v - bf2f(hh));
        }
        size_t o = (size_t)(cc >> 6) * HDC * Tq + (size_t)(cc & 63) * Tq + r0;
        *(bf16x4*)&Chi[o] = ph;
        *(bf16x4*)&Clo[o] = pl;
      }
    }
}

// ---------------------------------------------------------------------------
// Downsampled scores (exact fp32 mask path)
// ---------------------------------------------------------------------------
__global__ __launch_bounds__(256) void sd_kernel(
    const float* __restrict__ Q, const float* __restrict__ K,
    float* __restrict__ Sd) {
  __shared__ float Qs[64][68];
  __shared__ float Ks[64][68];
  int jk0 = blockIdx.x * 64, iq0 = blockIdx.y * 64, h = blockIdx.z;
  int tid = threadIdx.x, tx = tid & 15, ty = tid >> 4;
#pragma unroll
  for (int q = 0; q < 4; ++q) {
    int f = tid * 4 + q;
    int row = f >> 4, c4 = f & 15;
    float4 q4 = *(const float4*)&Q[((size_t)(iq0 + row) * 8) * Dm + h * HDC + c4 * 4];
    float4 k4 = *(const float4*)&K[((size_t)(jk0 + row) * 8) * Dm + h * HDC + c4 * 4];
    Qs[c4 * 4 + 0][row] = q4.x; Qs[c4 * 4 + 1][row] = q4.y;
    Qs[c4 * 4 + 2][row] = q4.z; Qs[c4 * 4 + 3][row] = q4.w;
    Ks[c4 * 4 + 0][row] = k4.x; Ks[c4 * 4 + 1][row] = k4.y;
    Ks[c4 * 4 + 2][row] = k4.z; Ks[c4 * 4 + 3][row] = k4.w;
  }
  __syncthreads();
  float acc[4][4] = {};
#pragma unroll
  for (int k = 0; k < 64; ++k) {
    float a[4], b[4];
#pragma unroll
    for (int i = 0; i < 4; ++i) { a[i] = Qs[k][ty * 4 + i]; b[i] = Ks[k][tx * 4 + i]; }
#pragma unroll
    for (int i = 0; i < 4; ++i)
#pragma unroll
      for (int j = 0; j < 4; ++j) acc[i][j] += a[i] * b[j];
  }
#pragma unroll
  for (int i = 0; i < 4; ++i)
#pragma unroll
    for (int j = 0; j < 4; ++j)
      Sd[(size_t)(h * TDC + iq0 + ty * 4 + i) * TDC + jk0 + tx * 4 + j] =
          acc[i][j] * 0.125f;
}

// ---------------------------------------------------------------------------
// 26th-largest of each 256-value Sd row
// ---------------------------------------------------------------------------
__global__ __launch_bounds__(64) void kth_kernel(
    const float* __restrict__ Sd, float* __restrict__ kth) {
  int b = blockIdx.x;
  int lane = threadIdx.x;
  const float* row = &Sd[(size_t)b * TDC];
  float v[4];
#pragma unroll
  for (int j = 0; j < 4; ++j) v[j] = row[lane + 64 * j];
  float ans = 0.f;
  for (int it = 0; it < KSEL; ++it) {
    float lm = fmaxf(fmaxf(v[0], v[1]), fmaxf(v[2], v[3]));
#pragma unroll
    for (int off = 1; off < 64; off <<= 1) lm = fmaxf(lm, __shfl_xor(lm, off));
    if (it == KSEL - 1) { ans = lm; break; }
    unsigned long long ball =
        __ballot(v[0] == lm || v[1] == lm || v[2] == lm || v[3] == lm);
    int first = __ffsll(ball) - 1;
    if (lane == first) {
      if (v[0] == lm) v[0] = -INFINITY;
      else if (v[1] == lm) v[1] = -INFINITY;
      else if (v[2] == lm) v[2] = -INFINITY;
      else v[3] = -INFINITY;
    }
  }
  if (lane == 0) kth[b] = ans;
}

// per-head mean of V over all 2048 rows (uniform all-masked regime)
__global__ __launch_bounds__(64) void vmean_kernel(
    const ushort* __restrict__ Vth, const ushort* __restrict__ Vtl,
    float* __restrict__ Vm) {
  int h = blockIdx.x, d = threadIdx.x;
  const ushort* rh = Vth + (size_t)h * HDC * Tq + (size_t)d * Tq;
  const ushort* rl = Vtl + (size_t)h * HDC * Tq + (size_t)d * Tq;
  float s = 0.f;
  for (int t = 0; t < Tq; t += 8) {
    bf16x8 a = *(const bf16x8*)&rh[t];
    bf16x8 b = *(const bf16x8*)&rl[t];
#pragma unroll
    for (int j = 0; j < 8; ++j) s += bf2f((ushort)a[j]) + bf2f((ushort)b[j]);
  }
  Vm[h * HDC + d] = s * (1.f / 2048.f);
}

// ---------------------------------------------------------------------------
// Split-j MFMA flash attention partial with split-bf16 QK^T and PV-V.
// grid (chunk 4, qt 32, head 16), block 256 (4 waves, 16 q-rows each).
// ---------------------------------------------------------------------------
__global__ __launch_bounds__(256) void attn_partial(
    const ushort* __restrict__ Qh, const ushort* __restrict__ Ql,
    const ushort* __restrict__ Kh, const ushort* __restrict__ Kl,
    const ushort* __restrict__ Vth, const ushort* __restrict__ Vtl,
    const float* __restrict__ U,
    const float* __restrict__ Sd, const float* __restrict__ kth,
    ushort* __restrict__ Pacc, float* __restrict__ Pm, float* __restrict__ Pl) {
  int c = blockIdx.x, qt = blockIdx.y, h = blockIdx.z;
  if (c * CH > qt) return;
  int tid = threadIdx.x, w = tid >> 6, l = tid & 63, l15 = l & 15, lg = l >> 4;
  int i0 = qt * 64;

  __shared__ ushort KhS[64][64], KlS[64][64], VhS[64][64], VlS[64][64];
  __shared__ ushort Ps[4][16][72];
  __shared__ float pen_s[64][8];
  __shared__ float u_s[64];

  if (tid < 64) {
    float uu = U[i0 + tid];
    u_s[tid] = 1.f + fminf(fmaxf(uu, 0.f), 1.f);
  }

  size_t qoff = ((size_t)h * Tq + i0 + 16 * w + l15) * HDC;
  bf16x8 qh0 = *(const bf16x8*)(Qh + qoff + lg * 8);
  bf16x8 qh1 = *(const bf16x8*)(Qh + qoff + 32 + lg * 8);
  bf16x8 ql0 = *(const bf16x8*)(Ql + qoff + lg * 8);
  bf16x8 ql1 = *(const bf16x8*)(Ql + qoff + 32 + lg * 8);

  float mrow[4], lrow[4];
#pragma unroll
  for (int r = 0; r < 4; ++r) { mrow[r] = -INFINITY; lrow[r] = 0.f; }
  f32x4 acc[4] = {};

  int i8base = qt * 8;
  const float* kthH = kth + h * TDC;
  const float* SdH = Sd + (size_t)h * TDC * TDC;

  int jt1 = min(c * CH + CH, qt + 1);
  for (int jt = c * CH; jt < jt1; ++jt) {
    int j0 = jt * 64;
    __syncthreads();
#pragma unroll
    for (int q = 0; q < 2; ++q) {
      int f = tid * 2 + q, row = f >> 3, c8 = f & 7;
      size_t ko = ((size_t)h * Tq + j0 + row) * HDC + c8 * 8;
      size_t vo = ((size_t)h * HDC + row) * Tq + j0 + c8 * 8;
      int sc = (c8 ^ (row & 7)) * 8;
      *(bf16x8*)&KhS[row][sc] = *(const bf16x8*)&Kh[ko];
      *(bf16x8*)&KlS[row][sc] = *(const bf16x8*)&Kl[ko];
      *(bf16x8*)&VhS[row][sc] = *(const bf16x8*)&Vth[vo];
      *(bf16x8*)&VlS[row][sc] = *(const bf16x8*)&Vtl[vo];
    }
    // mask penalties: 64 rows x 8 col-blocks, exact fp32 reference op order
#pragma unroll
    for (int q = 0; q < 2; ++q) {
      int v = tid + q * 256, r = v & 63, jb = v >> 6;
      float uu = u_s[r];
      int i8 = i8base + (r >> 3);
      float sdv = SdH[(size_t)i8 * TDC + (j0 >> 3) + jb];
      float kv = kthH[i8];
      float arg = (sdv * uu - kv * uu) * 10.f;
      float mk;
      if (arg >= 0.f) mk = 1.f / (1.f + expf(-arg));
      else { float e = expf(arg); mk = e / (1.f + e); }
      pen_s[r][jb] = (1.f - mk) * (-1.0e9f);
    }
    __syncthreads();

    // S = Q K^T  (split: 24 MFMA)
    f32x4 s[4] = {};
#pragma unroll
    for (int nt = 0; nt < 4; ++nt) {
      int kr = nt * 16 + l15;
      int s0 = ((0 + lg) ^ (kr & 7)) * 8;
      int s1 = ((4 + lg) ^ (kr & 7)) * 8;
      bf16x8 bh0 = *(const bf16x8*)&KhS[kr][s0];
      bf16x8 bh1 = *(const bf16x8*)&KhS[kr][s1];
      bf16x8 bl0 = *(const bf16x8*)&KlS[kr][s0];
      bf16x8 bl1 = *(const bf16x8*)&KlS[kr][s1];
      s[nt] = __builtin_amdgcn_mfma_f32_16x16x32_bf16(qh0, bh0, s[nt], 0, 0, 0);
      s[nt] = __builtin_amdgcn_mfma_f32_16x16x32_bf16(qh1, bh1, s[nt], 0, 0, 0);
      s[nt] = __builtin_amdgcn_mfma_f32_16x16x32_bf16(ql0, bh0, s[nt], 0, 0, 0);
      s[nt] = __builtin_amdgcn_mfma_f32_16x16x32_bf16(ql1, bh1, s[nt], 0, 0, 0);
      s[nt] = __builtin_amdgcn_mfma_f32_16x16x32_bf16(qh0, bl0, s[nt], 0, 0, 0);
      s[nt] = __builtin_amdgcn_mfma_f32_16x16x32_bf16(qh1, bl1, s[nt], 0, 0, 0);
    }

    bool diag = (jt == qt);
#pragma unroll
    for (int rg = 0; rg < 4; ++rg) {
      int rloc = lg * 4 + rg;
      int irow = i0 + 16 * w + rloc;
      float lgv[4];
#pragma unroll
      for (int nt = 0; nt < 4; ++nt) {
        int jcol = j0 + nt * 16 + l15;
        float pen = pen_s[16 * w + rloc][(nt * 16 + l15) >> 3];
        lgv[nt] = s[nt][rg] * 0.125f + ((diag && jcol > irow) ? -1.0e9f : pen);
      }
      float mt = fmaxf(fmaxf(lgv[0], lgv[1]), fmaxf(lgv[2], lgv[3]));
#pragma unroll
      for (int off = 1; off < 16; off <<= 1) mt = fmaxf(mt, __shfl_xor(mt, off));
      float mnew = fmaxf(mrow[rg], mt);
      float sc = __expf(mrow[rg] - mnew);
      float ps = 0.f; ushort pb[4];
#pragma unroll
      for (int nt = 0; nt < 4; ++nt) {
        float p = __expf(lgv[nt] - mnew);
        pb[nt] = f2bf(p);
        ps += bf2f(pb[nt]);   // denominator consistent with bf16 numerator
      }
#pragma unroll
      for (int off = 1; off < 16; off <<= 1) ps += __shfl_xor(ps, off);
      lrow[rg] = lrow[rg] * sc + ps;
      mrow[rg] = mnew;
#pragma unroll
      for (int nt = 0; nt < 4; ++nt) acc[nt][rg] *= sc;
#pragma unroll
      for (int nt = 0; nt < 4; ++nt) Ps[w][rloc][nt * 16 + l15] = pb[nt];
    }

    // O += P V  (split V: 16 MFMA)
#pragma unroll
    for (int kst = 0; kst < 2; ++kst) {
      bf16x8 pa = *(const bf16x8*)&Ps[w][l15][kst * 32 + lg * 8];
#pragma unroll
      for (int ntd = 0; ntd < 4; ++ntd) {
        int vr = ntd * 16 + l15;
        int sv = ((kst * 4 + lg) ^ (vr & 7)) * 8;
        bf16x8 vbh = *(const bf16x8*)&VhS[vr][sv];
        bf16x8 vbl = *(const bf16x8*)&VlS[vr][sv];
        acc[ntd] = __builtin_amdgcn_mfma_f32_16x16x32_bf16(pa, vbh, acc[ntd], 0, 0, 0);
        acc[ntd] = __builtin_amdgcn_mfma_f32_16x16x32_bf16(pa, vbl, acc[ntd], 0, 0, 0);
      }
    }
  }

  size_t rowbase = ((size_t)c * NHC + h) * Tq + i0 + 16 * w;
#pragma unroll
  for (int rg = 0; rg < 4; ++rg) {
    int rloc = lg * 4 + rg;
    if (l15 == 0) {
      Pm[rowbase + rloc] = mrow[rg];
      Pl[rowbase + rloc] = lrow[rg];
    }
#pragma unroll
    for (int ntd = 0; ntd < 4; ++ntd)
      Pacc[(rowbase + rloc) * HDC + ntd * 16 + l15] = f2bf(acc[ntd][rg]);
  }
}

// ---------------------------------------------------------------------------
// Merge split-j partials -> AO split bf16 hi/lo [t][1024]
// ---------------------------------------------------------------------------
__global__ __launch_bounds__(256) void attn_merge(
    const ushort* __restrict__ Pacc, const float* __restrict__ Pm,
    const float* __restrict__ Pl, const float* __restrict__ Vm,
    ushort* __restrict__ AOh, ushort* __restrict__ AOl) {
  int qt = blockIdx.x, h = blockIdx.y;
  int tid = threadIdx.x;
  int r = tid >> 2, q4 = tid & 3;
  int gi = qt * 64 + r;
  int nc = (qt >> 3) + 1;
  float M = -INFINITY, mv[4];
#pragma unroll
  for (int cc = 0; cc < 4; ++cc) {
    mv[cc] = (cc < nc) ? Pm[((size_t)cc * NHC + h) * Tq + gi] : -INFINITY;
    M = fmaxf(M, mv[cc]);
  }
  if (M == -1.0e9f) {   // all-masked: reference softmax uniform over ALL rows
#pragma unroll
    for (int dd = 0; dd < 16; dd += 4) {
      int d = q4 * 16 + dd;
      float4 v = *(const float4*)&Vm[h * HDC + d];
      float vv[4] = {v.x, v.y, v.z, v.w};
      ushort4 uh, ul;
      ushort* uhp = &uh.x; ushort* ulp = &ul.x;
#pragma unroll
      for (int j = 0; j < 4; ++j) {
        ushort hh = f2bf(vv[j]);
        uhp[j] = hh; ulp[j] = f2bf(vv[j] - bf2f(hh));
      }
      *(ushort4*)&AOh[(size_t)gi * Dm + h * HDC + d] = uh;
      *(ushort4*)&AOl[(size_t)gi * Dm + h * HDC + d] = ul;
    }
    return;
  }
  float W[4], L = 0.f;
#pragma unroll
  for (int cc = 0; cc < 4; ++cc) {
    W[cc] = (cc < nc) ? __expf(mv[cc] - M) : 0.f;
    if (cc < nc) L += Pl[((size_t)cc * NHC + h) * Tq + gi] * W[cc];
  }
  float invL = 1.f / L;
#pragma unroll
  for (int dd = 0; dd < 16; dd += 4) {
    int d = q4 * 16 + dd;
    float o[4] = {0.f, 0.f, 0.f, 0.f};
    for (int cc = 0; cc < nc; ++cc) {
      bf16x4 a = *(const bf16x4*)&Pacc[(((size_t)cc * NHC + h) * Tq + gi) * HDC + d];
#pragma unroll
      for (int j = 0; j < 4; ++j) o[j] += bf2f((ushort)a[j]) * W[cc];
    }
    ushort4 uh, ul;
    ushort* uhp = &uh.x; ushort* ulp = &ul.x;
#pragma unroll
    for (int j = 0; j < 4; ++j) {
      float vv = o[j] * invL;
      ushort hh = f2bf(vv);
      uhp[j] = hh; ulp[j] = f2bf(vv - bf2f(hh));
    }
    *(ushort4*)&AOh[(size_t)gi * Dm + h * HDC + d] = uh;
    *(ushort4*)&AOl[(size_t)gi * Dm + h * HDC + d] = ul;
  }
}

// ---------------------------------------------------------------------------
extern "C" void kernel_launch(void* const* d_in, const int* in_sizes, int n_in,
                              void* d_out, int out_size, void* d_ws, size_t ws_size,
                              hipStream_t stream) {
  const float* x  = (const float*)d_in[0];
  const float* U  = (const float*)d_in[1];
  const float* wq = (const float*)d_in[2];
  const float* wk = (const float*)d_in[3];
  const float* wv = (const float*)d_in[4];
  const float* wo = (const float*)d_in[5];
  float* out = (float*)d_out;

  float* fw = (float*)d_ws;
  const size_t TD_ = (size_t)Tq * Dm;          // 2M elements
  const size_t WW_ = (size_t)Dm * Dm;          // 1M elements
  float* Q   = fw;                 fw += TD_;
  float* Kf  = fw;                 fw += TD_;
  float* Sd  = fw;                 fw += (size_t)NHC * TDC * TDC;
  float* kth = fw;                 fw += 4096;
  float* Vm  = fw;                 fw += 4096;
  float* Pm  = fw;                 fw += 4 * NHC * Tq;
  float* Pl  = fw;                 fw += 4 * NHC * Tq;
  ushort* uw = (ushort*)fw;
  ushort* xh   = uw;               uw += TD_;
  ushort* xl   = uw;               uw += TD_;
  ushort* wvh  = uw;               uw += WW_;
  ushort* wvl  = uw;               uw += WW_;
  ushort* woh  = uw;               uw += WW_;
  ushort* wol  = uw;               uw += WW_;
  ushort* Qh   = uw;               uw += TD_;
  ushort* Ql   = uw;               uw += TD_;
  ushort* Kh   = uw;               uw += TD_;
  ushort* Kl   = uw;               uw += TD_;
  ushort* Vth  = uw;               uw += TD_;
  ushort* Vtl  = uw;               uw += TD_;
  ushort* AOh  = uw;               uw += TD_;
  ushort* AOl  = uw;               uw += TD_;
  ushort* Pacc = uw;               uw += (size_t)4 * NHC * Tq * HDC;

  dim3 bb(256);
  dim3 gg(Dm / 64, Tq / 64);
  // splits of inputs
  cast_split<<<dim3(TD_ / 1024), bb, 0, stream>>>(x, xh, xl);
  cast_split<<<dim3(WW_ / 1024), bb, 0, stream>>>(wv, wvh, wvl);
  cast_split<<<dim3(WW_ / 1024), bb, 0, stream>>>(wo, woh, wol);
  // exact fp32 Q, K (mask path)
  gemm_xwT<<<gg, bb, 0, stream>>>(x, wq, Q);
  gemm_xwT<<<gg, bb, 0, stream>>>(x, wk, Kf);
  // V via split-bf16 MFMA (fp32-quality), transposed split epilogue
  gemm_split<1><<<gg, bb, 0, stream>>>(xh, xl, wvh, wvl, nullptr, Vth, Vtl);
  // split Q,K for attention
  remap_qk_split<<<dim3(TD_ / 1024), bb, 0, stream>>>(Q, Kf, Qh, Ql, Kh, Kl);
  // mask precomputation (exact fp32)
  sd_kernel<<<dim3(4, 4, NHC), bb, 0, stream>>>(Q, Kf, Sd);
  kth_kernel<<<dim3(NHC * TDC), dim3(64), 0, stream>>>(Sd, kth);
  vmean_kernel<<<dim3(NHC), dim3(64), 0, stream>>>(Vth, Vtl, Vm);
  // split-j flash attention + merge
  attn_partial<<<dim3(4, Tq / 64, NHC), bb, 0, stream>>>(
      Qh, Ql, Kh, Kl, Vth, Vtl, U, Sd, kth, Pacc, Pm, Pl);
  attn_merge<<<dim3(Tq / 64, NHC), bb, 0, stream>>>(Pacc, Pm, Pl, Vm, AOh, AOl);
  // output projection via split-bf16 MFMA
  gemm_split<0><<<gg, bb, 0, stream>>>(AOh, AOl, woh, wol, out, nullptr, nullptr);
}

// Round 6
// 262.851 us; speedup vs baseline: 2.6541x; 1.4439x over previous
//
#include <hip/hip_runtime.h>
#include <hip/hip_bf16.h>
#include <cmath>

typedef __attribute__((ext_vector_type(8))) short bf16x8;
typedef __attribute__((ext_vector_type(4))) short bf16x4;
typedef __attribute__((ext_vector_type(4))) float f32x4;

constexpr int Tq  = 2048;
constexpr int Dm  = 1024;
constexpr int NHC = 16;
constexpr int HDC = 64;
constexpr int TDC = 256;
constexpr int KSEL = 26;   // ceil(204/8): 26th-largest distinct value
constexpr int CH  = 8;     // j-tiles (of 64) per split-j chunk

__device__ inline ushort f2bf(float x) {
  union { float f; unsigned u; } v; v.f = x;
  return (ushort)((v.u + 0x7FFF + ((v.u >> 16) & 1)) >> 16);
}
__device__ inline float bf2f(ushort b) {
  union { unsigned u; float f; } v; v.u = ((unsigned)b) << 16;
  return v.f;
}

// ---------------------------------------------------------------------------
// fp32 strided-row GEMM for the mask path only:
//   Qd[256][1024] = x[::8] @ wq^T,  Kd[256][1024] = x[::8] @ wk^T
// grid (16, 4, 2): z picks (wq->Qd) / (wk->Kd). Same accumulation structure
// as the round-3/5 exact path.
// ---------------------------------------------------------------------------
__global__ __launch_bounds__(256) void gemm_qkd(
    const float* __restrict__ x, const float* __restrict__ wq,
    const float* __restrict__ wk, float* __restrict__ Qd,
    float* __restrict__ Kd) {
  const int K = 1024, N = 1024;
  const float* B = blockIdx.z ? wk : wq;
  float* C = blockIdx.z ? Kd : Qd;
  __shared__ float As[32][68];
  __shared__ float Bs[32][68];
  int tid = threadIdx.x;
  int tx = tid & 15, ty = tid >> 4;
  int n0 = blockIdx.x * 64, m0 = blockIdx.y * 64;
  float acc[4][4] = {};
  for (int k0 = 0; k0 < K; k0 += 32) {
#pragma unroll
    for (int q = 0; q < 2; ++q) {
      int f = tid * 2 + q;
      int row = f >> 3, c4 = f & 7;
      float4 av = *(const float4*)&x[(size_t)((m0 + row) * 8) * K + k0 + c4 * 4];
      float4 bv = *(const float4*)&B[(size_t)(n0 + row) * K + k0 + c4 * 4];
      As[c4 * 4 + 0][row] = av.x; As[c4 * 4 + 1][row] = av.y;
      As[c4 * 4 + 2][row] = av.z; As[c4 * 4 + 3][row] = av.w;
      Bs[c4 * 4 + 0][row] = bv.x; Bs[c4 * 4 + 1][row] = bv.y;
      Bs[c4 * 4 + 2][row] = bv.z; Bs[c4 * 4 + 3][row] = bv.w;
    }
    __syncthreads();
#pragma unroll
    for (int k = 0; k < 32; ++k) {
      float a[4], b[4];
#pragma unroll
      for (int i = 0; i < 4; ++i) { a[i] = As[k][ty * 4 + i]; b[i] = Bs[k][tx * 4 + i]; }
#pragma unroll
      for (int i = 0; i < 4; ++i)
#pragma unroll
        for (int j = 0; j < 4; ++j) acc[i][j] += a[i] * b[j];
    }
    __syncthreads();
  }
#pragma unroll
  for (int i = 0; i < 4; ++i)
#pragma unroll
    for (int j = 0; j < 4; ++j)
      C[(size_t)(m0 + ty * 4 + i) * N + n0 + tx * 4 + j] = acc[i][j];
}

// ---------------------------------------------------------------------------
// fp32 -> (bf16 hi, bf16 lo) split cast
// ---------------------------------------------------------------------------
__global__ __launch_bounds__(256) void cast_split(
    const float* __restrict__ in, ushort* __restrict__ hi,
    ushort* __restrict__ lo) {
  int base = (blockIdx.x * 256 + threadIdx.x) * 4;
  float4 v = *(const float4*)&in[base];
  ushort h0 = f2bf(v.x), h1 = f2bf(v.y), h2 = f2bf(v.z), h3 = f2bf(v.w);
  *(ushort4*)&hi[base] = make_ushort4(h0, h1, h2, h3);
  *(ushort4*)&lo[base] = make_ushort4(
      f2bf(v.x - bf2f(h0)), f2bf(v.y - bf2f(h1)),
      f2bf(v.z - bf2f(h2)), f2bf(v.w - bf2f(h3)));
}

// ---------------------------------------------------------------------------
// Split-bf16 MFMA GEMM (fp32-quality): C = (Ah+Al)*(Bh+Bl)^T, drop Al*Bl.
// MODE 0: fp32 row-major out (out projection).
// MODE 1: bf16 HI-only transposed out Vt[h][d][t] (attention V).
// MODE 3: split bf16 head-major out [h][t][d] hi/lo (attention Q, K).
// ---------------------------------------------------------------------------
template <int MODE>
__global__ __launch_bounds__(256) void gemm_split(
    const ushort* __restrict__ Ah, const ushort* __restrict__ Al,
    const ushort* __restrict__ Bh, const ushort* __restrict__ Bl,
    float* __restrict__ Cf, ushort* __restrict__ Chi, ushort* __restrict__ Clo) {
  __shared__ ushort AhS[64][64], AlS[64][64], BhS[64][64], BlS[64][64];
  int tid = threadIdx.x, w = tid >> 6, l = tid & 63, l15 = l & 15, lg = l >> 4;
  int wm = (w >> 1) * 32, wn = (w & 1) * 32;
  int m0 = blockIdx.y * 64, n0 = blockIdx.x * 64;
  f32x4 acc[2][2] = {};
  for (int k0 = 0; k0 < Dm; k0 += 64) {
    __syncthreads();
#pragma unroll
    for (int q = 0; q < 2; ++q) {
      int f = tid * 2 + q, row = f >> 3, c8 = f & 7;
      size_t ao = (size_t)(m0 + row) * Dm + k0 + c8 * 8;
      size_t bo = (size_t)(n0 + row) * Dm + k0 + c8 * 8;
      int sc = (c8 ^ (row & 7)) * 8;
      *(bf16x8*)&AhS[row][sc] = *(const bf16x8*)&Ah[ao];
      *(bf16x8*)&AlS[row][sc] = *(const bf16x8*)&Al[ao];
      *(bf16x8*)&BhS[row][sc] = *(const bf16x8*)&Bh[bo];
      *(bf16x8*)&BlS[row][sc] = *(const bf16x8*)&Bl[bo];
    }
    __syncthreads();
#pragma unroll
    for (int kst = 0; kst < 2; ++kst) {
      bf16x8 ah[2], al[2], bh[2], bl[2];
#pragma unroll
      for (int i = 0; i < 2; ++i) {
        int ar = wm + i * 16 + l15;
        int sa = ((kst * 4 + lg) ^ (ar & 7)) * 8;
        ah[i] = *(const bf16x8*)&AhS[ar][sa];
        al[i] = *(const bf16x8*)&AlS[ar][sa];
        int br = wn + i * 16 + l15;
        int sb = ((kst * 4 + lg) ^ (br & 7)) * 8;
        bh[i] = *(const bf16x8*)&BhS[br][sb];
        bl[i] = *(const bf16x8*)&BlS[br][sb];
      }
#pragma unroll
      for (int i = 0; i < 2; ++i)
#pragma unroll
        for (int j = 0; j < 2; ++j) {
          acc[i][j] = __builtin_amdgcn_mfma_f32_16x16x32_bf16(ah[i], bh[j], acc[i][j], 0, 0, 0);
          acc[i][j] = __builtin_amdgcn_mfma_f32_16x16x32_bf16(al[i], bh[j], acc[i][j], 0, 0, 0);
          acc[i][j] = __builtin_amdgcn_mfma_f32_16x16x32_bf16(ah[i], bl[j], acc[i][j], 0, 0, 0);
        }
    }
  }
#pragma unroll
  for (int i = 0; i < 2; ++i)
#pragma unroll
    for (int j = 0; j < 2; ++j) {
      int r0 = m0 + wm + i * 16 + lg * 4;
      int cc = n0 + wn + j * 16 + l15;
      if (MODE == 0) {
#pragma unroll
        for (int rg = 0; rg < 4; ++rg)
          Cf[(size_t)(r0 + rg) * Dm + cc] = acc[i][j][rg];
      } else if (MODE == 1) {
        bf16x4 ph;
#pragma unroll
        for (int rg = 0; rg < 4; ++rg) ph[rg] = (short)f2bf(acc[i][j][rg]);
        size_t o = (size_t)(cc >> 6) * HDC * Tq + (size_t)(cc & 63) * Tq + r0;
        *(bf16x4*)&Chi[o] = ph;
      } else {  // MODE 3: [h][t][d] hi/lo
        size_t o = (size_t)(cc >> 6) * Tq * HDC + (size_t)r0 * HDC + (cc & 63);
#pragma unroll
        for (int rg = 0; rg < 4; ++rg) {
          float v = acc[i][j][rg];
          ushort hh = f2bf(v);
          Chi[o + (size_t)rg * HDC] = hh;
          Clo[o + (size_t)rg * HDC] = f2bf(v - bf2f(hh));
        }
      }
    }
}

// ---------------------------------------------------------------------------
// Downsampled scores from dense Qd/Kd (exact fp32 mask path)
// ---------------------------------------------------------------------------
__global__ __launch_bounds__(256) void sd_kernel(
    const float* __restrict__ Qd, const float* __restrict__ Kd,
    float* __restrict__ Sd) {
  __shared__ float Qs[64][68];
  __shared__ float Ks[64][68];
  int jk0 = blockIdx.x * 64, iq0 = blockIdx.y * 64, h = blockIdx.z;
  int tid = threadIdx.x, tx = tid & 15, ty = tid >> 4;
#pragma unroll
  for (int q = 0; q < 4; ++q) {
    int f = tid * 4 + q;
    int row = f >> 4, c4 = f & 15;
    float4 q4 = *(const float4*)&Qd[(size_t)(iq0 + row) * Dm + h * HDC + c4 * 4];
    float4 k4 = *(const float4*)&Kd[(size_t)(jk0 + row) * Dm + h * HDC + c4 * 4];
    Qs[c4 * 4 + 0][row] = q4.x; Qs[c4 * 4 + 1][row] = q4.y;
    Qs[c4 * 4 + 2][row] = q4.z; Qs[c4 * 4 + 3][row] = q4.w;
    Ks[c4 * 4 + 0][row] = k4.x; Ks[c4 * 4 + 1][row] = k4.y;
    Ks[c4 * 4 + 2][row] = k4.z; Ks[c4 * 4 + 3][row] = k4.w;
  }
  __syncthreads();
  float acc[4][4] = {};
#pragma unroll
  for (int k = 0; k < 64; ++k) {
    float a[4], b[4];
#pragma unroll
    for (int i = 0; i < 4; ++i) { a[i] = Qs[k][ty * 4 + i]; b[i] = Ks[k][tx * 4 + i]; }
#pragma unroll
    for (int i = 0; i < 4; ++i)
#pragma unroll
      for (int j = 0; j < 4; ++j) acc[i][j] += a[i] * b[j];
  }
#pragma unroll
  for (int i = 0; i < 4; ++i)
#pragma unroll
    for (int j = 0; j < 4; ++j)
      Sd[(size_t)(h * TDC + iq0 + ty * 4 + i) * TDC + jk0 + tx * 4 + j] =
          acc[i][j] * 0.125f;
}

// ---------------------------------------------------------------------------
// 26th-largest of each 256-value Sd row
// ---------------------------------------------------------------------------
__global__ __launch_bounds__(64) void kth_kernel(
    const float* __restrict__ Sd, float* __restrict__ kth) {
  int b = blockIdx.x;
  int lane = threadIdx.x;
  const float* row = &Sd[(size_t)b * TDC];
  float v[4];
#pragma unroll
  for (int j = 0; j < 4; ++j) v[j] = row[lane + 64 * j];
  float ans = 0.f;
  for (int it = 0; it < KSEL; ++it) {
    float lm = fmaxf(fmaxf(v[0], v[1]), fmaxf(v[2], v[3]));
#pragma unroll
    for (int off = 1; off < 64; off <<= 1) lm = fmaxf(lm, __shfl_xor(lm, off));
    if (it == KSEL - 1) { ans = lm; break; }
    unsigned long long ball =
        __ballot(v[0] == lm || v[1] == lm || v[2] == lm || v[3] == lm);
    int first = __ffsll(ball) - 1;
    if (lane == first) {
      if (v[0] == lm) v[0] = -INFINITY;
      else if (v[1] == lm) v[1] = -INFINITY;
      else if (v[2] == lm) v[2] = -INFINITY;
      else v[3] = -INFINITY;
    }
  }
  if (lane == 0) kth[b] = ans;
}

// ---------------------------------------------------------------------------
// Vmean via algebra: mean_t(V) = mean_t(x) @ wv^T.
// ---------------------------------------------------------------------------
__global__ __launch_bounds__(256) void xpart_kernel(
    const float* __restrict__ x, float* __restrict__ xp) {
  int b = blockIdx.x, t = threadIdx.x;
  float4 s = {0.f, 0.f, 0.f, 0.f};
  for (int r = 0; r < 32; ++r) {
    float4 v = *(const float4*)&x[(size_t)(b * 32 + r) * Dm + t * 4];
    s.x += v.x; s.y += v.y; s.z += v.z; s.w += v.w;
  }
  *(float4*)&xp[b * Dm + t * 4] = s;
}
__global__ __launch_bounds__(256) void xmean2_kernel(
    const float* __restrict__ xp, float* __restrict__ xm) {
  int t = threadIdx.x;
  float4 s = {0.f, 0.f, 0.f, 0.f};
  for (int i = 0; i < 64; ++i) {
    float4 v = *(const float4*)&xp[i * Dm + t * 4];
    s.x += v.x; s.y += v.y; s.z += v.z; s.w += v.w;
  }
  float4 o = {s.x * (1.f / 2048.f), s.y * (1.f / 2048.f),
              s.z * (1.f / 2048.f), s.w * (1.f / 2048.f)};
  *(float4*)&xm[t * 4] = o;
}
__global__ __launch_bounds__(256) void vm_kernel(
    const float* __restrict__ xm, const float* __restrict__ wv,
    float* __restrict__ Vm) {
  int h = blockIdx.x, t = threadIdx.x;
  int r = h * 64 + (t >> 2), q = t & 3;
  const float* wrow = wv + (size_t)r * Dm + q * 256;
  const float* a = xm + q * 256;
  float s = 0.f;
  for (int k = 0; k < 256; k += 4) {
    float4 w4 = *(const float4*)&wrow[k];
    float4 a4 = *(const float4*)&a[k];
    s += w4.x * a4.x + w4.y * a4.y + w4.z * a4.z + w4.w * a4.w;
  }
  s += __shfl_xor(s, 1); s += __shfl_xor(s, 2);
  if (q == 0) Vm[r] = s;
}

// ---------------------------------------------------------------------------
// Split-j MFMA flash attention partial. Split-bf16 QK^T, hi-only PV.
// grid (80 active (c,qt) pairs, 16 heads), block 256 (4 waves x 16 q-rows).
// ---------------------------------------------------------------------------
__global__ __launch_bounds__(256) void attn_partial(
    const ushort* __restrict__ Qh, const ushort* __restrict__ Ql,
    const ushort* __restrict__ Kh, const ushort* __restrict__ Kl,
    const ushort* __restrict__ Vth, const float* __restrict__ U,
    const float* __restrict__ Sd, const float* __restrict__ kth,
    ushort* __restrict__ Pacc, float* __restrict__ Pm, float* __restrict__ Pl) {
  int p = blockIdx.x, h = blockIdx.y;
  int c, qt;
  if (p < 32)      { c = 0; qt = p; }
  else if (p < 56) { c = 1; qt = p - 24; }
  else if (p < 72) { c = 2; qt = p - 40; }
  else             { c = 3; qt = p - 48; }
  int tid = threadIdx.x, w = tid >> 6, l = tid & 63, l15 = l & 15, lg = l >> 4;
  int i0 = qt * 64;

  __shared__ ushort KhS[64][64], KlS[64][64], VhS[64][64];
  __shared__ ushort Ps[4][16][72];
  __shared__ float pen_s[64][8];
  __shared__ float u_s[64];

  if (tid < 64) {
    float uu = U[i0 + tid];
    u_s[tid] = 1.f + fminf(fmaxf(uu, 0.f), 1.f);
  }

  size_t qoff = ((size_t)h * Tq + i0 + 16 * w + l15) * HDC;
  bf16x8 qh0 = *(const bf16x8*)(Qh + qoff + lg * 8);
  bf16x8 qh1 = *(const bf16x8*)(Qh + qoff + 32 + lg * 8);
  bf16x8 ql0 = *(const bf16x8*)(Ql + qoff + lg * 8);
  bf16x8 ql1 = *(const bf16x8*)(Ql + qoff + 32 + lg * 8);

  float mrow[4], lrow[4];
#pragma unroll
  for (int r = 0; r < 4; ++r) { mrow[r] = -INFINITY; lrow[r] = 0.f; }
  f32x4 acc[4] = {};

  int i8base = qt * 8;
  const float* kthH = kth + h * TDC;
  const float* SdH = Sd + (size_t)h * TDC * TDC;

  int jt1 = min(c * CH + CH, qt + 1);
  for (int jt = c * CH; jt < jt1; ++jt) {
    int j0 = jt * 64;
    __syncthreads();
#pragma unroll
    for (int q = 0; q < 2; ++q) {
      int f = tid * 2 + q, row = f >> 3, c8 = f & 7;
      size_t ko = ((size_t)h * Tq + j0 + row) * HDC + c8 * 8;
      size_t vo = ((size_t)h * HDC + row) * Tq + j0 + c8 * 8;
      int sc = (c8 ^ (row & 7)) * 8;
      *(bf16x8*)&KhS[row][sc] = *(const bf16x8*)&Kh[ko];
      *(bf16x8*)&KlS[row][sc] = *(const bf16x8*)&Kl[ko];
      *(bf16x8*)&VhS[row][sc] = *(const bf16x8*)&Vth[vo];
    }
    // mask penalties, exact fp32 reference op order
#pragma unroll
    for (int q = 0; q < 2; ++q) {
      int v = tid + q * 256, r = v & 63, jb = v >> 6;
      float uu = u_s[r];
      int i8 = i8base + (r >> 3);
      float sdv = SdH[(size_t)i8 * TDC + (j0 >> 3) + jb];
      float kv = kthH[i8];
      float arg = (sdv * uu - kv * uu) * 10.f;
      float mk;
      if (arg >= 0.f) mk = 1.f / (1.f + expf(-arg));
      else { float e = expf(arg); mk = e / (1.f + e); }
      pen_s[r][jb] = (1.f - mk) * (-1.0e9f);
    }
    __syncthreads();

    // S = Q K^T  (split: 24 MFMA)
    f32x4 s[4] = {};
#pragma unroll
    for (int nt = 0; nt < 4; ++nt) {
      int kr = nt * 16 + l15;
      int s0 = ((0 + lg) ^ (kr & 7)) * 8;
      int s1 = ((4 + lg) ^ (kr & 7)) * 8;
      bf16x8 bh0 = *(const bf16x8*)&KhS[kr][s0];
      bf16x8 bh1 = *(const bf16x8*)&KhS[kr][s1];
      bf16x8 bl0 = *(const bf16x8*)&KlS[kr][s0];
      bf16x8 bl1 = *(const bf16x8*)&KlS[kr][s1];
      s[nt] = __builtin_amdgcn_mfma_f32_16x16x32_bf16(qh0, bh0, s[nt], 0, 0, 0);
      s[nt] = __builtin_amdgcn_mfma_f32_16x16x32_bf16(qh1, bh1, s[nt], 0, 0, 0);
      s[nt] = __builtin_amdgcn_mfma_f32_16x16x32_bf16(ql0, bh0, s[nt], 0, 0, 0);
      s[nt] = __builtin_amdgcn_mfma_f32_16x16x32_bf16(ql1, bh1, s[nt], 0, 0, 0);
      s[nt] = __builtin_amdgcn_mfma_f32_16x16x32_bf16(qh0, bl0, s[nt], 0, 0, 0);
      s[nt] = __builtin_amdgcn_mfma_f32_16x16x32_bf16(qh1, bl1, s[nt], 0, 0, 0);
    }

    bool diag = (jt == qt);
#pragma unroll
    for (int rg = 0; rg < 4; ++rg) {
      int rloc = lg * 4 + rg;
      int irow = i0 + 16 * w + rloc;
      float lgv[4];
#pragma unroll
      for (int nt = 0; nt < 4; ++nt) {
        int jcol = j0 + nt * 16 + l15;
        float pen = pen_s[16 * w + rloc][(nt * 16 + l15) >> 3];
        lgv[nt] = s[nt][rg] * 0.125f + ((diag && jcol > irow) ? -1.0e9f : pen);
      }
      float mt = fmaxf(fmaxf(lgv[0], lgv[1]), fmaxf(lgv[2], lgv[3]));
#pragma unroll
      for (int off = 1; off < 16; off <<= 1) mt = fmaxf(mt, __shfl_xor(mt, off));
      float mnew = fmaxf(mrow[rg], mt);
      float sc = __expf(mrow[rg] - mnew);
      float ps = 0.f; ushort pb[4];
#pragma unroll
      for (int nt = 0; nt < 4; ++nt) {
        float pv = __expf(lgv[nt] - mnew);
        pb[nt] = f2bf(pv);
        ps += bf2f(pb[nt]);   // denominator consistent with bf16 numerator
      }
#pragma unroll
      for (int off = 1; off < 16; off <<= 1) ps += __shfl_xor(ps, off);
      lrow[rg] = lrow[rg] * sc + ps;
      mrow[rg] = mnew;
#pragma unroll
      for (int nt = 0; nt < 4; ++nt) acc[nt][rg] *= sc;
#pragma unroll
      for (int nt = 0; nt < 4; ++nt) Ps[w][rloc][nt * 16 + l15] = pb[nt];
    }

    // O += P V  (hi-only V: 8 MFMA)
#pragma unroll
    for (int kst = 0; kst < 2; ++kst) {
      bf16x8 pa = *(const bf16x8*)&Ps[w][l15][kst * 32 + lg * 8];
#pragma unroll
      for (int ntd = 0; ntd < 4; ++ntd) {
        int vr = ntd * 16 + l15;
        int sv = ((kst * 4 + lg) ^ (vr & 7)) * 8;
        bf16x8 vbh = *(const bf16x8*)&VhS[vr][sv];
        acc[ntd] = __builtin_amdgcn_mfma_f32_16x16x32_bf16(pa, vbh, acc[ntd], 0, 0, 0);
      }
    }
  }

  size_t rowbase = ((size_t)c * NHC + h) * Tq + i0 + 16 * w;
#pragma unroll
  for (int rg = 0; rg < 4; ++rg) {
    int rloc = lg * 4 + rg;
    if (l15 == 0) {
      Pm[rowbase + rloc] = mrow[rg];
      Pl[rowbase + rloc] = lrow[rg];
    }
#pragma unroll
    for (int ntd = 0; ntd < 4; ++ntd)
      Pacc[(rowbase + rloc) * HDC + ntd * 16 + l15] = f2bf(acc[ntd][rg]);
  }
}

// ---------------------------------------------------------------------------
// Merge split-j partials -> AO split bf16 hi/lo [t][1024]
// ---------------------------------------------------------------------------
__global__ __launch_bounds__(256) void attn_merge(
    const ushort* __restrict__ Pacc, const float* __restrict__ Pm,
    const float* __restrict__ Pl, const float* __restrict__ Vm,
    ushort* __restrict__ AOh, ushort* __restrict__ AOl) {
  int qt = blockIdx.x, h = blockIdx.y;
  int tid = threadIdx.x;
  int r = tid >> 2, q4 = tid & 3;
  int gi = qt * 64 + r;
  int nc = (qt >> 3) + 1;
  float M = -INFINITY, mv[4];
#pragma unroll
  for (int cc = 0; cc < 4; ++cc) {
    mv[cc] = (cc < nc) ? Pm[((size_t)cc * NHC + h) * Tq + gi] : -INFINITY;
    M = fmaxf(M, mv[cc]);
  }
  if (M == -1.0e9f) {   // all-masked: reference softmax uniform over ALL rows
#pragma unroll
    for (int dd = 0; dd < 16; dd += 4) {
      int d = q4 * 16 + dd;
      float4 v = *(const float4*)&Vm[h * HDC + d];
      float vv[4] = {v.x, v.y, v.z, v.w};
      ushort4 uh, ul;
      ushort* uhp = &uh.x; ushort* ulp = &ul.x;
#pragma unroll
      for (int j = 0; j < 4; ++j) {
        ushort hh = f2bf(vv[j]);
        uhp[j] = hh; ulp[j] = f2bf(vv[j] - bf2f(hh));
      }
      *(ushort4*)&AOh[(size_t)gi * Dm + h * HDC + d] = uh;
      *(ushort4*)&AOl[(size_t)gi * Dm + h * HDC + d] = ul;
    }
    return;
  }
  float W[4], L = 0.f;
#pragma unroll
  for (int cc = 0; cc < 4; ++cc) {
    W[cc] = (cc < nc) ? __expf(mv[cc] - M) : 0.f;
    if (cc < nc) L += Pl[((size_t)cc * NHC + h) * Tq + gi] * W[cc];
  }
  float invL = 1.f / L;
#pragma unroll
  for (int dd = 0; dd < 16; dd += 4) {
    int d = q4 * 16 + dd;
    float o[4] = {0.f, 0.f, 0.f, 0.f};
    for (int cc = 0; cc < nc; ++cc) {
      bf16x4 a = *(const bf16x4*)&Pacc[(((size_t)cc * NHC + h) * Tq + gi) * HDC + d];
#pragma unroll
      for (int j = 0; j < 4; ++j) o[j] += bf2f((ushort)a[j]) * W[cc];
    }
    ushort4 uh, ul;
    ushort* uhp = &uh.x; ushort* ulp = &ul.x;
#pragma unroll
    for (int j = 0; j < 4; ++j) {
      float vv = o[j] * invL;
      ushort hh = f2bf(vv);
      uhp[j] = hh; ulp[j] = f2bf(vv - bf2f(hh));
    }
    *(ushort4*)&AOh[(size_t)gi * Dm + h * HDC + d] = uh;
    *(ushort4*)&AOl[(size_t)gi * Dm + h * HDC + d] = ul;
  }
}

// ---------------------------------------------------------------------------
extern "C" void kernel_launch(void* const* d_in, const int* in_sizes, int n_in,
                              void* d_out, int out_size, void* d_ws, size_t ws_size,
                              hipStream_t stream) {
  const float* x  = (const float*)d_in[0];
  const float* U  = (const float*)d_in[1];
  const float* wq = (const float*)d_in[2];
  const float* wk = (const float*)d_in[3];
  const float* wv = (const float*)d_in[4];
  const float* wo = (const float*)d_in[5];
  float* out = (float*)d_out;

  float* fw = (float*)d_ws;
  const size_t TD_ = (size_t)Tq * Dm;          // 2M elements
  const size_t WW_ = (size_t)Dm * Dm;          // 1M elements
  const size_t QD_ = (size_t)TDC * Dm;         // 256K elements
  float* Qd  = fw;                 fw += QD_;
  float* Kd  = fw;                 fw += QD_;
  float* Sd  = fw;                 fw += (size_t)NHC * TDC * TDC;
  float* kth = fw;                 fw += 4096;
  float* Vm  = fw;                 fw += 4096;
  float* xm  = fw;                 fw += 4096;
  float* xp  = fw;                 fw += 64 * Dm;
  float* Pm  = fw;                 fw += 4 * NHC * Tq;
  float* Pl  = fw;                 fw += 4 * NHC * Tq;
  ushort* uw = (ushort*)fw;
  ushort* xh   = uw;               uw += TD_;
  ushort* xl   = uw;               uw += TD_;
  ushort* wqh  = uw;               uw += WW_;
  ushort* wql  = uw;               uw += WW_;
  ushort* wkh  = uw;               uw += WW_;
  ushort* wkl  = uw;               uw += WW_;
  ushort* wvh  = uw;               uw += WW_;
  ushort* wvl  = uw;               uw += WW_;
  ushort* woh  = uw;               uw += WW_;
  ushort* wol  = uw;               uw += WW_;
  ushort* Qh   = uw;               uw += TD_;
  ushort* Ql   = uw;               uw += TD_;
  ushort* Kh   = uw;               uw += TD_;
  ushort* Kl   = uw;               uw += TD_;
  ushort* Vth  = uw;               uw += TD_;
  ushort* Pacc = uw;               uw += (size_t)4 * NHC * Tq * HDC;
  // AO aliases x's split buffers (lifetimes disjoint: xh/xl last read by
  // gemm_split V; AOh/AOl first written by attn_merge)
  ushort* AOh = xh;
  ushort* AOl = xl;

  dim3 bb(256);
  dim3 gg(Dm / 64, Tq / 64);
  // splits
  cast_split<<<dim3(TD_ / 1024), bb, 0, stream>>>(x, xh, xl);
  cast_split<<<dim3(WW_ / 1024), bb, 0, stream>>>(wq, wqh, wql);
  cast_split<<<dim3(WW_ / 1024), bb, 0, stream>>>(wk, wkh, wkl);
  cast_split<<<dim3(WW_ / 1024), bb, 0, stream>>>(wv, wvh, wvl);
  cast_split<<<dim3(WW_ / 1024), bb, 0, stream>>>(wo, woh, wol);
  // exact fp32 strided Qd/Kd (mask path only)
  gemm_qkd<<<dim3(Dm / 64, TDC / 64, 2), bb, 0, stream>>>(x, wq, wk, Qd, Kd);
  // attention Q/K/V via split-bf16 MFMA, fused layout epilogues
  gemm_split<3><<<gg, bb, 0, stream>>>(xh, xl, wqh, wql, nullptr, Qh, Ql);
  gemm_split<3><<<gg, bb, 0, stream>>>(xh, xl, wkh, wkl, nullptr, Kh, Kl);
  gemm_split<1><<<gg, bb, 0, stream>>>(xh, xl, wvh, wvl, nullptr, Vth, nullptr);
  // mask precomputation (exact fp32)
  sd_kernel<<<dim3(4, 4, NHC), bb, 0, stream>>>(Qd, Kd, Sd);
  kth_kernel<<<dim3(NHC * TDC), dim3(64), 0, stream>>>(Sd, kth);
  // Vmean = mean(x) @ wv^T
  xpart_kernel<<<dim3(64), bb, 0, stream>>>(x, xp);
  xmean2_kernel<<<dim3(1), bb, 0, stream>>>(xp, xm);
  vm_kernel<<<dim3(NHC), bb, 0, stream>>>(xm, wv, Vm);
  // split-j flash attention + merge
  attn_partial<<<dim3(80, NHC), bb, 0, stream>>>(
      Qh, Ql, Kh, Kl, Vth, U, Sd, kth, Pacc, Pm, Pl);
  attn_merge<<<dim3(Tq / 64, NHC), bb, 0, stream>>>(Pacc, Pm, Pl, Vm, AOh, AOl);
  // output projection via split-bf16 MFMA
  gemm_split<0><<<gg, bb, 0, stream>>>(AOh, AOl, woh, wol, out, nullptr, nullptr);
}

// Round 7
// 242.597 us; speedup vs baseline: 2.8757x; 1.0835x over previous
//
#include <hip/hip_runtime.h>
#include <hip/hip_bf16.h>
#include <cmath>

typedef __attribute__((ext_vector_type(8))) short bf16x8;
typedef __attribute__((ext_vector_type(4))) short bf16x4;
typedef __attribute__((ext_vector_type(4))) float f32x4;

constexpr int Tq  = 2048;
constexpr int Dm  = 1024;
constexpr int NHC = 16;
constexpr int HDC = 64;
constexpr int TDC = 256;
constexpr int KSEL = 26;   // ceil(204/8): 26th-largest distinct value
constexpr int CH  = 8;     // j-tiles (of 64) per split-j chunk

__device__ inline ushort f2bf(float x) {
  union { float f; unsigned u; } v; v.f = x;
  return (ushort)((v.u + 0x7FFF + ((v.u >> 16) & 1)) >> 16);
}
__device__ inline float bf2f(ushort b) {
  union { unsigned u; float f; } v; v.u = ((unsigned)b) << 16;
  return v.f;
}

// ---------------------------------------------------------------------------
// fp32 strided-row GEMM for the mask path only (exact):
//   Qd[256][1024] = x[::8] @ wq^T,  Kd[256][1024] = x[::8] @ wk^T
// ---------------------------------------------------------------------------
__global__ __launch_bounds__(256) void gemm_qkd(
    const float* __restrict__ x, const float* __restrict__ wq,
    const float* __restrict__ wk, float* __restrict__ Qd,
    float* __restrict__ Kd) {
  const int K = 1024, N = 1024;
  const float* B = blockIdx.z ? wk : wq;
  float* C = blockIdx.z ? Kd : Qd;
  __shared__ float As[32][68];
  __shared__ float Bs[32][68];
  int tid = threadIdx.x;
  int tx = tid & 15, ty = tid >> 4;
  int n0 = blockIdx.x * 64, m0 = blockIdx.y * 64;
  float acc[4][4] = {};
  for (int k0 = 0; k0 < K; k0 += 32) {
#pragma unroll
    for (int q = 0; q < 2; ++q) {
      int f = tid * 2 + q;
      int row = f >> 3, c4 = f & 7;
      float4 av = *(const float4*)&x[(size_t)((m0 + row) * 8) * K + k0 + c4 * 4];
      float4 bv = *(const float4*)&B[(size_t)(n0 + row) * K + k0 + c4 * 4];
      As[c4 * 4 + 0][row] = av.x; As[c4 * 4 + 1][row] = av.y;
      As[c4 * 4 + 2][row] = av.z; As[c4 * 4 + 3][row] = av.w;
      Bs[c4 * 4 + 0][row] = bv.x; Bs[c4 * 4 + 1][row] = bv.y;
      Bs[c4 * 4 + 2][row] = bv.z; Bs[c4 * 4 + 3][row] = bv.w;
    }
    __syncthreads();
#pragma unroll
    for (int k = 0; k < 32; ++k) {
      float a[4], b[4];
#pragma unroll
      for (int i = 0; i < 4; ++i) { a[i] = As[k][ty * 4 + i]; b[i] = Bs[k][tx * 4 + i]; }
#pragma unroll
      for (int i = 0; i < 4; ++i)
#pragma unroll
        for (int j = 0; j < 4; ++j) acc[i][j] += a[i] * b[j];
    }
    __syncthreads();
  }
#pragma unroll
  for (int i = 0; i < 4; ++i)
#pragma unroll
    for (int j = 0; j < 4; ++j)
      C[(size_t)(m0 + ty * 4 + i) * N + n0 + tx * 4 + j] = acc[i][j];
}

// ---------------------------------------------------------------------------
// Fused split-cast of x + 4 weight matrices in ONE launch.
// grid (2048, 5): z=0 -> x (2048 blocks of 1024 elems), z=1..4 -> weights
// (first 1024 blocks active).
// ---------------------------------------------------------------------------
__global__ __launch_bounds__(256) void cast_split_all(
    const float* __restrict__ x,  const float* __restrict__ wq,
    const float* __restrict__ wk, const float* __restrict__ wv,
    const float* __restrict__ wo,
    ushort* __restrict__ xh,  ushort* __restrict__ xl,
    ushort* __restrict__ wqh, ushort* __restrict__ wql,
    ushort* __restrict__ wkh, ushort* __restrict__ wkl,
    ushort* __restrict__ wvh, ushort* __restrict__ wvl,
    ushort* __restrict__ woh, ushort* __restrict__ wol) {
  int z = blockIdx.y, blk = blockIdx.x;
  const float* src; ushort *hi, *lo;
  if (z == 0)      { src = x;  hi = xh;  lo = xl; }
  else if (z == 1) { if (blk >= 1024) return; src = wq; hi = wqh; lo = wql; }
  else if (z == 2) { if (blk >= 1024) return; src = wk; hi = wkh; lo = wkl; }
  else if (z == 3) { if (blk >= 1024) return; src = wv; hi = wvh; lo = wvl; }
  else             { if (blk >= 1024) return; src = wo; hi = woh; lo = wol; }
  int base = (blk * 256 + threadIdx.x) * 4;
  float4 v = *(const float4*)&src[base];
  ushort h0 = f2bf(v.x), h1 = f2bf(v.y), h2 = f2bf(v.z), h3 = f2bf(v.w);
  *(ushort4*)&hi[base] = make_ushort4(h0, h1, h2, h3);
  *(ushort4*)&lo[base] = make_ushort4(
      f2bf(v.x - bf2f(h0)), f2bf(v.y - bf2f(h1)),
      f2bf(v.z - bf2f(h2)), f2bf(v.w - bf2f(h3)));
}

// ---------------------------------------------------------------------------
// Fused Q/K/V split-bf16 MFMA GEMM: 128x64 tile, 8 waves, BK=64.
// grid (N/64=16, M/128=16, 3): z=0 -> Q [h][t][d] hi/lo, z=1 -> K same,
// z=2 -> V transposed hi-only Vt[h][d][t].
// Numerics identical to round-6 gemm_split (same MFMA term order, fp32 acc).
// ---------------------------------------------------------------------------
__global__ __launch_bounds__(512) void gemm_qkv(
    const ushort* __restrict__ xh_, const ushort* __restrict__ xl_,
    const ushort* __restrict__ wqh_, const ushort* __restrict__ wql_,
    const ushort* __restrict__ wkh_, const ushort* __restrict__ wkl_,
    const ushort* __restrict__ wvh_, const ushort* __restrict__ wvl_,
    ushort* __restrict__ Qh, ushort* __restrict__ Ql,
    ushort* __restrict__ Kh, ushort* __restrict__ Kl,
    ushort* __restrict__ Vth) {
  int z = blockIdx.z;
  const ushort* Bh = (z == 0) ? wqh_ : ((z == 1) ? wkh_ : wvh_);
  const ushort* Bl = (z == 0) ? wql_ : ((z == 1) ? wkl_ : wvl_);
  __shared__ ushort AhS[128][64], AlS[128][64], BhS[64][64], BlS[64][64];
  int tid = threadIdx.x;
  int w = tid >> 6, l = tid & 63, l15 = l & 15, lg = l >> 4;
  int wr = w >> 1, wc = w & 1;
  int m0 = blockIdx.y * 128, n0 = blockIdx.x * 64;
  f32x4 acc[2][2] = {};
  for (int k0 = 0; k0 < Dm; k0 += 64) {
    __syncthreads();
#pragma unroll
    for (int q = 0; q < 2; ++q) {
      int f = tid * 2 + q, row = f >> 3, c8 = f & 7;
      size_t ao = (size_t)(m0 + row) * Dm + k0 + c8 * 8;
      int sc = (c8 ^ (row & 7)) * 8;
      *(bf16x8*)&AhS[row][sc] = *(const bf16x8*)&xh_[ao];
      *(bf16x8*)&AlS[row][sc] = *(const bf16x8*)&xl_[ao];
    }
    {
      int row = tid >> 3, c8 = tid & 7;
      size_t bo = (size_t)(n0 + row) * Dm + k0 + c8 * 8;
      int sc = (c8 ^ (row & 7)) * 8;
      *(bf16x8*)&BhS[row][sc] = *(const bf16x8*)&Bh[bo];
      *(bf16x8*)&BlS[row][sc] = *(const bf16x8*)&Bl[bo];
    }
    __syncthreads();
#pragma unroll
    for (int kst = 0; kst < 2; ++kst) {
      bf16x8 ah[2], al[2], bh[2], bl[2];
#pragma unroll
      for (int i = 0; i < 2; ++i) {
        int ar = wr * 32 + i * 16 + l15;
        int sa = ((kst * 4 + lg) ^ (ar & 7)) * 8;
        ah[i] = *(const bf16x8*)&AhS[ar][sa];
        al[i] = *(const bf16x8*)&AlS[ar][sa];
        int br = wc * 32 + i * 16 + l15;
        int sb = ((kst * 4 + lg) ^ (br & 7)) * 8;
        bh[i] = *(const bf16x8*)&BhS[br][sb];
        bl[i] = *(const bf16x8*)&BlS[br][sb];
      }
#pragma unroll
      for (int i = 0; i < 2; ++i)
#pragma unroll
        for (int j = 0; j < 2; ++j) {
          acc[i][j] = __builtin_amdgcn_mfma_f32_16x16x32_bf16(ah[i], bh[j], acc[i][j], 0, 0, 0);
          acc[i][j] = __builtin_amdgcn_mfma_f32_16x16x32_bf16(al[i], bh[j], acc[i][j], 0, 0, 0);
          acc[i][j] = __builtin_amdgcn_mfma_f32_16x16x32_bf16(ah[i], bl[j], acc[i][j], 0, 0, 0);
        }
    }
  }
#pragma unroll
  for (int i = 0; i < 2; ++i)
#pragma unroll
    for (int j = 0; j < 2; ++j) {
      int r0 = m0 + wr * 32 + i * 16 + lg * 4;
      int cc = n0 + wc * 32 + j * 16 + l15;
      if (z <= 1) {  // Q or K: [h][t][d] split hi/lo
        ushort* Chi = (z == 0) ? Qh : Kh;
        ushort* Clo = (z == 0) ? Ql : Kl;
        size_t o = (size_t)(cc >> 6) * Tq * HDC + (size_t)r0 * HDC + (cc & 63);
#pragma unroll
        for (int rg = 0; rg < 4; ++rg) {
          float v = acc[i][j][rg];
          ushort hh = f2bf(v);
          Chi[o + (size_t)rg * HDC] = hh;
          Clo[o + (size_t)rg * HDC] = f2bf(v - bf2f(hh));
        }
      } else {       // V: Vt[h][d][t] hi only
        bf16x4 ph;
#pragma unroll
        for (int rg = 0; rg < 4; ++rg) ph[rg] = (short)f2bf(acc[i][j][rg]);
        size_t o = (size_t)(cc >> 6) * HDC * Tq + (size_t)(cc & 63) * Tq + r0;
        *(bf16x4*)&Vth[o] = ph;
      }
    }
}

// ---------------------------------------------------------------------------
// Output projection: out = (AOh+AOl) @ (woh+wol)^T, fp32 out. Same structure.
// grid (16, 16), 512 threads.
// ---------------------------------------------------------------------------
__global__ __launch_bounds__(512) void gemm_out(
    const ushort* __restrict__ Ah, const ushort* __restrict__ Al,
    const ushort* __restrict__ Bh, const ushort* __restrict__ Bl,
    float* __restrict__ Cf) {
  __shared__ ushort AhS[128][64], AlS[128][64], BhS[64][64], BlS[64][64];
  int tid = threadIdx.x;
  int w = tid >> 6, l = tid & 63, l15 = l & 15, lg = l >> 4;
  int wr = w >> 1, wc = w & 1;
  int m0 = blockIdx.y * 128, n0 = blockIdx.x * 64;
  f32x4 acc[2][2] = {};
  for (int k0 = 0; k0 < Dm; k0 += 64) {
    __syncthreads();
#pragma unroll
    for (int q = 0; q < 2; ++q) {
      int f = tid * 2 + q, row = f >> 3, c8 = f & 7;
      size_t ao = (size_t)(m0 + row) * Dm + k0 + c8 * 8;
      int sc = (c8 ^ (row & 7)) * 8;
      *(bf16x8*)&AhS[row][sc] = *(const bf16x8*)&Ah[ao];
      *(bf16x8*)&AlS[row][sc] = *(const bf16x8*)&Al[ao];
    }
    {
      int row = tid >> 3, c8 = tid & 7;
      size_t bo = (size_t)(n0 + row) * Dm + k0 + c8 * 8;
      int sc = (c8 ^ (row & 7)) * 8;
      *(bf16x8*)&BhS[row][sc] = *(const bf16x8*)&Bh[bo];
      *(bf16x8*)&BlS[row][sc] = *(const bf16x8*)&Bl[bo];
    }
    __syncthreads();
#pragma unroll
    for (int kst = 0; kst < 2; ++kst) {
      bf16x8 ah[2], al[2], bh[2], bl[2];
#pragma unroll
      for (int i = 0; i < 2; ++i) {
        int ar = wr * 32 + i * 16 + l15;
        int sa = ((kst * 4 + lg) ^ (ar & 7)) * 8;
        ah[i] = *(const bf16x8*)&AhS[ar][sa];
        al[i] = *(const bf16x8*)&AlS[ar][sa];
        int br = wc * 32 + i * 16 + l15;
        int sb = ((kst * 4 + lg) ^ (br & 7)) * 8;
        bh[i] = *(const bf16x8*)&BhS[br][sb];
        bl[i] = *(const bf16x8*)&BlS[br][sb];
      }
#pragma unroll
      for (int i = 0; i < 2; ++i)
#pragma unroll
        for (int j = 0; j < 2; ++j) {
          acc[i][j] = __builtin_amdgcn_mfma_f32_16x16x32_bf16(ah[i], bh[j], acc[i][j], 0, 0, 0);
          acc[i][j] = __builtin_amdgcn_mfma_f32_16x16x32_bf16(al[i], bh[j], acc[i][j], 0, 0, 0);
          acc[i][j] = __builtin_amdgcn_mfma_f32_16x16x32_bf16(ah[i], bl[j], acc[i][j], 0, 0, 0);
        }
    }
  }
#pragma unroll
  for (int i = 0; i < 2; ++i)
#pragma unroll
    for (int j = 0; j < 2; ++j) {
      int r0 = m0 + wr * 32 + i * 16 + lg * 4;
      int cc = n0 + wc * 32 + j * 16 + l15;
#pragma unroll
      for (int rg = 0; rg < 4; ++rg)
        Cf[(size_t)(r0 + rg) * Dm + cc] = acc[i][j][rg];
    }
}

// ---------------------------------------------------------------------------
// Downsampled scores from dense Qd/Kd (exact fp32 mask path)
// ---------------------------------------------------------------------------
__global__ __launch_bounds__(256) void sd_kernel(
    const float* __restrict__ Qd, const float* __restrict__ Kd,
    float* __restrict__ Sd) {
  __shared__ float Qs[64][68];
  __shared__ float Ks[64][68];
  int jk0 = blockIdx.x * 64, iq0 = blockIdx.y * 64, h = blockIdx.z;
  int tid = threadIdx.x, tx = tid & 15, ty = tid >> 4;
#pragma unroll
  for (int q = 0; q < 4; ++q) {
    int f = tid * 4 + q;
    int row = f >> 4, c4 = f & 15;
    float4 q4 = *(const float4*)&Qd[(size_t)(iq0 + row) * Dm + h * HDC + c4 * 4];
    float4 k4 = *(const float4*)&Kd[(size_t)(jk0 + row) * Dm + h * HDC + c4 * 4];
    Qs[c4 * 4 + 0][row] = q4.x; Qs[c4 * 4 + 1][row] = q4.y;
    Qs[c4 * 4 + 2][row] = q4.z; Qs[c4 * 4 + 3][row] = q4.w;
    Ks[c4 * 4 + 0][row] = k4.x; Ks[c4 * 4 + 1][row] = k4.y;
    Ks[c4 * 4 + 2][row] = k4.z; Ks[c4 * 4 + 3][row] = k4.w;
  }
  __syncthreads();
  float acc[4][4] = {};
#pragma unroll
  for (int k = 0; k < 64; ++k) {
    float a[4], b[4];
#pragma unroll
    for (int i = 0; i < 4; ++i) { a[i] = Qs[k][ty * 4 + i]; b[i] = Ks[k][tx * 4 + i]; }
#pragma unroll
    for (int i = 0; i < 4; ++i)
#pragma unroll
      for (int j = 0; j < 4; ++j) acc[i][j] += a[i] * b[j];
  }
#pragma unroll
  for (int i = 0; i < 4; ++i)
#pragma unroll
    for (int j = 0; j < 4; ++j)
      Sd[(size_t)(h * TDC + iq0 + ty * 4 + i) * TDC + jk0 + tx * 4 + j] =
          acc[i][j] * 0.125f;
}

// ---------------------------------------------------------------------------
// 26th-largest of each 256-value Sd row
// ---------------------------------------------------------------------------
__global__ __launch_bounds__(64) void kth_kernel(
    const float* __restrict__ Sd, float* __restrict__ kth) {
  int b = blockIdx.x;
  int lane = threadIdx.x;
  const float* row = &Sd[(size_t)b * TDC];
  float v[4];
#pragma unroll
  for (int j = 0; j < 4; ++j) v[j] = row[lane + 64 * j];
  float ans = 0.f;
  for (int it = 0; it < KSEL; ++it) {
    float lm = fmaxf(fmaxf(v[0], v[1]), fmaxf(v[2], v[3]));
#pragma unroll
    for (int off = 1; off < 64; off <<= 1) lm = fmaxf(lm, __shfl_xor(lm, off));
    if (it == KSEL - 1) { ans = lm; break; }
    unsigned long long ball =
        __ballot(v[0] == lm || v[1] == lm || v[2] == lm || v[3] == lm);
    int first = __ffsll(ball) - 1;
    if (lane == first) {
      if (v[0] == lm) v[0] = -INFINITY;
      else if (v[1] == lm) v[1] = -INFINITY;
      else if (v[2] == lm) v[2] = -INFINITY;
      else v[3] = -INFINITY;
    }
  }
  if (lane == 0) kth[b] = ans;
}

// ---------------------------------------------------------------------------
// Vmean via algebra: mean_t(V) = mean_t(x) @ wv^T.
// ---------------------------------------------------------------------------
__global__ __launch_bounds__(256) void xpart_kernel(
    const float* __restrict__ x, float* __restrict__ xp) {
  int b = blockIdx.x, t = threadIdx.x;
  float4 s = {0.f, 0.f, 0.f, 0.f};
  for (int r = 0; r < 32; ++r) {
    float4 v = *(const float4*)&x[(size_t)(b * 32 + r) * Dm + t * 4];
    s.x += v.x; s.y += v.y; s.z += v.z; s.w += v.w;
  }
  *(float4*)&xp[b * Dm + t * 4] = s;
}
__global__ __launch_bounds__(256) void xmean2_kernel(
    const float* __restrict__ xp, float* __restrict__ xm) {
  int t = threadIdx.x;
  float4 s = {0.f, 0.f, 0.f, 0.f};
  for (int i = 0; i < 64; ++i) {
    float4 v = *(const float4*)&xp[i * Dm + t * 4];
    s.x += v.x; s.y += v.y; s.z += v.z; s.w += v.w;
  }
  float4 o = {s.x * (1.f / 2048.f), s.y * (1.f / 2048.f),
              s.z * (1.f / 2048.f), s.w * (1.f / 2048.f)};
  *(float4*)&xm[t * 4] = o;
}
__global__ __launch_bounds__(256) void vm_kernel(
    const float* __restrict__ xm, const float* __restrict__ wv,
    float* __restrict__ Vm) {
  int h = blockIdx.x, t = threadIdx.x;
  int r = h * 64 + (t >> 2), q = t & 3;
  const float* wrow = wv + (size_t)r * Dm + q * 256;
  const float* a = xm + q * 256;
  float s = 0.f;
  for (int k = 0; k < 256; k += 4) {
    float4 w4 = *(const float4*)&wrow[k];
    float4 a4 = *(const float4*)&a[k];
    s += w4.x * a4.x + w4.y * a4.y + w4.z * a4.z + w4.w * a4.w;
  }
  s += __shfl_xor(s, 1); s += __shfl_xor(s, 2);
  if (q == 0) Vm[r] = s;
}

// ---------------------------------------------------------------------------
// Split-j MFMA flash attention partial. Split-bf16 QK^T, hi-only PV.
// grid (80 active (c,qt) pairs, 16 heads), block 256 (4 waves x 16 q-rows).
// ---------------------------------------------------------------------------
__global__ __launch_bounds__(256) void attn_partial(
    const ushort* __restrict__ Qh, const ushort* __restrict__ Ql,
    const ushort* __restrict__ Kh, const ushort* __restrict__ Kl,
    const ushort* __restrict__ Vth, const float* __restrict__ U,
    const float* __restrict__ Sd, const float* __restrict__ kth,
    ushort* __restrict__ Pacc, float* __restrict__ Pm, float* __restrict__ Pl) {
  int p = blockIdx.x, h = blockIdx.y;
  int c, qt;
  if (p < 32)      { c = 0; qt = p; }
  else if (p < 56) { c = 1; qt = p - 24; }
  else if (p < 72) { c = 2; qt = p - 40; }
  else             { c = 3; qt = p - 48; }
  int tid = threadIdx.x, w = tid >> 6, l = tid & 63, l15 = l & 15, lg = l >> 4;
  int i0 = qt * 64;

  __shared__ ushort KhS[64][64], KlS[64][64], VhS[64][64];
  __shared__ ushort Ps[4][16][72];
  __shared__ float pen_s[64][8];
  __shared__ float u_s[64];

  if (tid < 64) {
    float uu = U[i0 + tid];
    u_s[tid] = 1.f + fminf(fmaxf(uu, 0.f), 1.f);
  }

  size_t qoff = ((size_t)h * Tq + i0 + 16 * w + l15) * HDC;
  bf16x8 qh0 = *(const bf16x8*)(Qh + qoff + lg * 8);
  bf16x8 qh1 = *(const bf16x8*)(Qh + qoff + 32 + lg * 8);
  bf16x8 ql0 = *(const bf16x8*)(Ql + qoff + lg * 8);
  bf16x8 ql1 = *(const bf16x8*)(Ql + qoff + 32 + lg * 8);

  float mrow[4], lrow[4];
#pragma unroll
  for (int r = 0; r < 4; ++r) { mrow[r] = -INFINITY; lrow[r] = 0.f; }
  f32x4 acc[4] = {};

  int i8base = qt * 8;
  const float* kthH = kth + h * TDC;
  const float* SdH = Sd + (size_t)h * TDC * TDC;

  int jt1 = min(c * CH + CH, qt + 1);
  for (int jt = c * CH; jt < jt1; ++jt) {
    int j0 = jt * 64;
    __syncthreads();
#pragma unroll
    for (int q = 0; q < 2; ++q) {
      int f = tid * 2 + q, row = f >> 3, c8 = f & 7;
      size_t ko = ((size_t)h * Tq + j0 + row) * HDC + c8 * 8;
      size_t vo = ((size_t)h * HDC + row) * Tq + j0 + c8 * 8;
      int sc = (c8 ^ (row & 7)) * 8;
      *(bf16x8*)&KhS[row][sc] = *(const bf16x8*)&Kh[ko];
      *(bf16x8*)&KlS[row][sc] = *(const bf16x8*)&Kl[ko];
      *(bf16x8*)&VhS[row][sc] = *(const bf16x8*)&Vth[vo];
    }
    // mask penalties, exact fp32 reference op order
#pragma unroll
    for (int q = 0; q < 2; ++q) {
      int v = tid + q * 256, r = v & 63, jb = v >> 6;
      float uu = u_s[r];
      int i8 = i8base + (r >> 3);
      float sdv = SdH[(size_t)i8 * TDC + (j0 >> 3) + jb];
      float kv = kthH[i8];
      float arg = (sdv * uu - kv * uu) * 10.f;
      float mk;
      if (arg >= 0.f) mk = 1.f / (1.f + expf(-arg));
      else { float e = expf(arg); mk = e / (1.f + e); }
      pen_s[r][jb] = (1.f - mk) * (-1.0e9f);
    }
    __syncthreads();

    // S = Q K^T  (split: 24 MFMA)
    f32x4 s[4] = {};
#pragma unroll
    for (int nt = 0; nt < 4; ++nt) {
      int kr = nt * 16 + l15;
      int s0 = ((0 + lg) ^ (kr & 7)) * 8;
      int s1 = ((4 + lg) ^ (kr & 7)) * 8;
      bf16x8 bh0 = *(const bf16x8*)&KhS[kr][s0];
      bf16x8 bh1 = *(const bf16x8*)&KhS[kr][s1];
      bf16x8 bl0 = *(const bf16x8*)&KlS[kr][s0];
      bf16x8 bl1 = *(const bf16x8*)&KlS[kr][s1];
      s[nt] = __builtin_amdgcn_mfma_f32_16x16x32_bf16(qh0, bh0, s[nt], 0, 0, 0);
      s[nt] = __builtin_amdgcn_mfma_f32_16x16x32_bf16(qh1, bh1, s[nt], 0, 0, 0);
      s[nt] = __builtin_amdgcn_mfma_f32_16x16x32_bf16(ql0, bh0, s[nt], 0, 0, 0);
      s[nt] = __builtin_amdgcn_mfma_f32_16x16x32_bf16(ql1, bh1, s[nt], 0, 0, 0);
      s[nt] = __builtin_amdgcn_mfma_f32_16x16x32_bf16(qh0, bl0, s[nt], 0, 0, 0);
      s[nt] = __builtin_amdgcn_mfma_f32_16x16x32_bf16(qh1, bl1, s[nt], 0, 0, 0);
    }

    bool diag = (jt == qt);
#pragma unroll
    for (int rg = 0; rg < 4; ++rg) {
      int rloc = lg * 4 + rg;
      int irow = i0 + 16 * w + rloc;
      float lgv[4];
#pragma unroll
      for (int nt = 0; nt < 4; ++nt) {
        int jcol = j0 + nt * 16 + l15;
        float pen = pen_s[16 * w + rloc][(nt * 16 + l15) >> 3];
        lgv[nt] = s[nt][rg] * 0.125f + ((diag && jcol > irow) ? -1.0e9f : pen);
      }
      float mt = fmaxf(fmaxf(lgv[0], lgv[1]), fmaxf(lgv[2], lgv[3]));
#pragma unroll
      for (int off = 1; off < 16; off <<= 1) mt = fmaxf(mt, __shfl_xor(mt, off));
      float mnew = fmaxf(mrow[rg], mt);
      float sc = __expf(mrow[rg] - mnew);
      float ps = 0.f; ushort pb[4];
#pragma unroll
      for (int nt = 0; nt < 4; ++nt) {
        float pv = __expf(lgv[nt] - mnew);
        pb[nt] = f2bf(pv);
        ps += bf2f(pb[nt]);   // denominator consistent with bf16 numerator
      }
#pragma unroll
      for (int off = 1; off < 16; off <<= 1) ps += __shfl_xor(ps, off);
      lrow[rg] = lrow[rg] * sc + ps;
      mrow[rg] = mnew;
#pragma unroll
      for (int nt = 0; nt < 4; ++nt) acc[nt][rg] *= sc;
#pragma unroll
      for (int nt = 0; nt < 4; ++nt) Ps[w][rloc][nt * 16 + l15] = pb[nt];
    }

    // O += P V  (hi-only V: 8 MFMA)
#pragma unroll
    for (int kst = 0; kst < 2; ++kst) {
      bf16x8 pa = *(const bf16x8*)&Ps[w][l15][kst * 32 + lg * 8];
#pragma unroll
      for (int ntd = 0; ntd < 4; ++ntd) {
        int vr = ntd * 16 + l15;
        int sv = ((kst * 4 + lg) ^ (vr & 7)) * 8;
        bf16x8 vbh = *(const bf16x8*)&VhS[vr][sv];
        acc[ntd] = __builtin_amdgcn_mfma_f32_16x16x32_bf16(pa, vbh, acc[ntd], 0, 0, 0);
      }
    }
  }

  size_t rowbase = ((size_t)c * NHC + h) * Tq + i0 + 16 * w;
#pragma unroll
  for (int rg = 0; rg < 4; ++rg) {
    int rloc = lg * 4 + rg;
    if (l15 == 0) {
      Pm[rowbase + rloc] = mrow[rg];
      Pl[rowbase + rloc] = lrow[rg];
    }
#pragma unroll
    for (int ntd = 0; ntd < 4; ++ntd)
      Pacc[(rowbase + rloc) * HDC + ntd * 16 + l15] = f2bf(acc[ntd][rg]);
  }
}

// ---------------------------------------------------------------------------
// Merge split-j partials -> AO split bf16 hi/lo [t][1024]
// ---------------------------------------------------------------------------
__global__ __launch_bounds__(256) void attn_merge(
    const ushort* __restrict__ Pacc, const float* __restrict__ Pm,
    const float* __restrict__ Pl, const float* __restrict__ Vm,
    ushort* __restrict__ AOh, ushort* __restrict__ AOl) {
  int qt = blockIdx.x, h = blockIdx.y;
  int tid = threadIdx.x;
  int r = tid >> 2, q4 = tid & 3;
  int gi = qt * 64 + r;
  int nc = (qt >> 3) + 1;
  float M = -INFINITY, mv[4];
#pragma unroll
  for (int cc = 0; cc < 4; ++cc) {
    mv[cc] = (cc < nc) ? Pm[((size_t)cc * NHC + h) * Tq + gi] : -INFINITY;
    M = fmaxf(M, mv[cc]);
  }
  if (M == -1.0e9f) {   // all-masked: reference softmax uniform over ALL rows
#pragma unroll
    for (int dd = 0; dd < 16; dd += 4) {
      int d = q4 * 16 + dd;
      float4 v = *(const float4*)&Vm[h * HDC + d];
      float vv[4] = {v.x, v.y, v.z, v.w};
      ushort4 uh, ul;
      ushort* uhp = &uh.x; ushort* ulp = &ul.x;
#pragma unroll
      for (int j = 0; j < 4; ++j) {
        ushort hh = f2bf(vv[j]);
        uhp[j] = hh; ulp[j] = f2bf(vv[j] - bf2f(hh));
      }
      *(ushort4*)&AOh[(size_t)gi * Dm + h * HDC + d] = uh;
      *(ushort4*)&AOl[(size_t)gi * Dm + h * HDC + d] = ul;
    }
    return;
  }
  float W[4], L = 0.f;
#pragma unroll
  for (int cc = 0; cc < 4; ++cc) {
    W[cc] = (cc < nc) ? __expf(mv[cc] - M) : 0.f;
    if (cc < nc) L += Pl[((size_t)cc * NHC + h) * Tq + gi] * W[cc];
  }
  float invL = 1.f / L;
#pragma unroll
  for (int dd = 0; dd < 16; dd += 4) {
    int d = q4 * 16 + dd;
    float o[4] = {0.f, 0.f, 0.f, 0.f};
    for (int cc = 0; cc < nc; ++cc) {
      bf16x4 a = *(const bf16x4*)&Pacc[(((size_t)cc * NHC + h) * Tq + gi) * HDC + d];
#pragma unroll
      for (int j = 0; j < 4; ++j) o[j] += bf2f((ushort)a[j]) * W[cc];
    }
    ushort4 uh, ul;
    ushort* uhp = &uh.x; ushort* ulp = &ul.x;
#pragma unroll
    for (int j = 0; j < 4; ++j) {
      float vv = o[j] * invL;
      ushort hh = f2bf(vv);
      uhp[j] = hh; ulp[j] = f2bf(vv - bf2f(hh));
    }
    *(ushort4*)&AOh[(size_t)gi * Dm + h * HDC + d] = uh;
    *(ushort4*)&AOl[(size_t)gi * Dm + h * HDC + d] = ul;
  }
}

// ---------------------------------------------------------------------------
extern "C" void kernel_launch(void* const* d_in, const int* in_sizes, int n_in,
                              void* d_out, int out_size, void* d_ws, size_t ws_size,
                              hipStream_t stream) {
  const float* x  = (const float*)d_in[0];
  const float* U  = (const float*)d_in[1];
  const float* wq = (const float*)d_in[2];
  const float* wk = (const float*)d_in[3];
  const float* wv = (const float*)d_in[4];
  const float* wo = (const float*)d_in[5];
  float* out = (float*)d_out;

  float* fw = (float*)d_ws;
  const size_t TD_ = (size_t)Tq * Dm;          // 2M elements
  const size_t WW_ = (size_t)Dm * Dm;          // 1M elements
  const size_t QD_ = (size_t)TDC * Dm;         // 256K elements
  float* Qd  = fw;                 fw += QD_;
  float* Kd  = fw;                 fw += QD_;
  float* Sd  = fw;                 fw += (size_t)NHC * TDC * TDC;
  float* kth = fw;                 fw += 4096;
  float* Vm  = fw;                 fw += 4096;
  float* xm  = fw;                 fw += 4096;
  float* xp  = fw;                 fw += 64 * Dm;
  float* Pm  = fw;                 fw += 4 * NHC * Tq;
  float* Pl  = fw;                 fw += 4 * NHC * Tq;
  ushort* uw = (ushort*)fw;
  ushort* xh   = uw;               uw += TD_;
  ushort* xl   = uw;               uw += TD_;
  ushort* wqh  = uw;               uw += WW_;
  ushort* wql  = uw;               uw += WW_;
  ushort* wkh  = uw;               uw += WW_;
  ushort* wkl  = uw;               uw += WW_;
  ushort* wvh  = uw;               uw += WW_;
  ushort* wvl  = uw;               uw += WW_;
  ushort* woh  = uw;               uw += WW_;
  ushort* wol  = uw;               uw += WW_;
  ushort* Qh   = uw;               uw += TD_;
  ushort* Ql   = uw;               uw += TD_;
  ushort* Kh   = uw;               uw += TD_;
  ushort* Kl   = uw;               uw += TD_;
  ushort* Vth  = uw;               uw += TD_;
  ushort* Pacc = uw;               uw += (size_t)4 * NHC * Tq * HDC;
  // AO aliases x's split buffers (lifetimes disjoint: xh/xl last read by
  // gemm_qkv; AOh/AOl first written by attn_merge)
  ushort* AOh = xh;
  ushort* AOl = xl;

  dim3 bb(256);
  // fused splits (1 launch)
  cast_split_all<<<dim3(2048, 5), bb, 0, stream>>>(
      x, wq, wk, wv, wo, xh, xl, wqh, wql, wkh, wkl, wvh, wvl, woh, wol);
  // exact fp32 strided Qd/Kd (mask path only)
  gemm_qkd<<<dim3(Dm / 64, TDC / 64, 2), bb, 0, stream>>>(x, wq, wk, Qd, Kd);
  // fused attention Q/K/V via split-bf16 MFMA, 128x64 tiles, 8 waves
  gemm_qkv<<<dim3(Dm / 64, Tq / 128, 3), dim3(512), 0, stream>>>(
      xh, xl, wqh, wql, wkh, wkl, wvh, wvl, Qh, Ql, Kh, Kl, Vth);
  // mask precomputation (exact fp32)
  sd_kernel<<<dim3(4, 4, NHC), bb, 0, stream>>>(Qd, Kd, Sd);
  kth_kernel<<<dim3(NHC * TDC), dim3(64), 0, stream>>>(Sd, kth);
  // Vmean = mean(x) @ wv^T
  xpart_kernel<<<dim3(64), bb, 0, stream>>>(x, xp);
  xmean2_kernel<<<dim3(1), bb, 0, stream>>>(xp, xm);
  vm_kernel<<<dim3(NHC), bb, 0, stream>>>(xm, wv, Vm);
  // split-j flash attention + merge
  attn_partial<<<dim3(80, NHC), bb, 0, stream>>>(
      Qh, Ql, Kh, Kl, Vth, U, Sd, kth, Pacc, Pm, Pl);
  attn_merge<<<dim3(Tq / 64, NHC), bb, 0, stream>>>(Pacc, Pm, Pl, Vm, AOh, AOl);
  // output projection via split-bf16 MFMA, 128x64 tiles
  gemm_out<<<dim3(Dm / 64, Tq / 128), dim3(512), 0, stream>>>(
      AOh, AOl, woh, wol, out);
}